// Round 9
// baseline (296.790 us; speedup 1.0000x reference)
//
#include <hip/hip_runtime.h>
#include <hip/hip_bf16.h>

// ---------------------------------------------------------------------------
// GCN (3x GCNConv) + dense head, bf16 MFMA.
// Round 9: 256x256 8-phase counted-vmcnt GEMM (T2+T3+T4+T5, m201-style) for
// the two big GEMMs. ks-major LDS regions (contiguous 16KB stage units),
// uniform vmcnt(10) gates, (8,4,0) tail, bank-conflict-free swizzled reads.
// 128x128 2-phase kernel retained for the small GEMMs. MPAD 20096 -> 20224
// (256-divisible).
// ---------------------------------------------------------------------------

typedef __attribute__((ext_vector_type(8))) short bf16x8;
typedef __attribute__((ext_vector_type(8))) unsigned short u16x8;
typedef __attribute__((ext_vector_type(4))) float f32x4;
typedef unsigned short u16;

#define MPAD 20224   // 79 * 256
#define AS1 __attribute__((address_space(1)))
#define AS3 __attribute__((address_space(3)))

__device__ inline u16 f2b(float f) {
  union { float f; unsigned int u; } x; x.f = f;
  unsigned int r = x.u + 0x7FFFu + ((x.u >> 16) & 1u);   // RNE
  return (u16)(r >> 16);
}
__device__ inline float b2f(u16 u) {
  union { unsigned int u; float f; } x; x.u = ((unsigned int)u) << 16; return x.f;
}
__device__ inline unsigned int cvt_pk_bf16(float lo, float hi) {
  unsigned int r;
  asm("v_cvt_pk_bf16_f32 %0, %1, %2" : "=v"(r) : "v"(lo), "v"(hi));
  return r;
}
template <int N> __device__ __forceinline__ void vmw() {
  asm volatile("s_waitcnt vmcnt(%0)" :: "i"(N) : "memory");
}
__device__ __forceinline__ void cfence() { asm volatile("" ::: "memory"); }

// ----------------------- fused prep kernel ---------------------------------

__device__ inline void wT_tile(const float* __restrict__ W, u16* __restrict__ WT,
                               int K, int N, int KPAD, int NPAD,
                               int bx, int by, float (*tile)[33]) {
  const int kb = by * 32, nb = bx * 32;
  const int tx = threadIdx.x & 31, ty = threadIdx.x >> 5;
  #pragma unroll
  for (int i = 0; i < 4; ++i) {
    int k = kb + ty + i * 8, n = nb + tx;
    tile[ty + i * 8][tx] = (k < K && n < N) ? W[(size_t)k * N + n] : 0.f;
  }
  __syncthreads();
  #pragma unroll
  for (int i = 0; i < 4; ++i) {
    int n = nb + ty + i * 8, k = kb + tx;
    WT[(size_t)n * KPAD + k] = f2b(tile[tx][ty + i * 8]);
  }
}

__global__ __launch_bounds__(256) void prep_all(
    const float* __restrict__ x, u16* __restrict__ xb,
    const float* __restrict__ W1, u16* __restrict__ w1t,
    const float* __restrict__ W2, u16* __restrict__ w2t,
    const float* __restrict__ W3, u16* __restrict__ w3t,
    const float* __restrict__ Wd1, u16* __restrict__ wd1t,
    const float* __restrict__ Wd2, u16* __restrict__ wd2t,
    const float* __restrict__ bd1, float* __restrict__ bd1p,
    const float* __restrict__ bd2, float* __restrict__ bd2p,
    const int* __restrict__ dst, int* __restrict__ cnt1,
    int* __restrict__ cnt2) {
  __shared__ float tile[32][33];
  const int b = blockIdx.x;
  const int tid = threadIdx.x;
  if (b < 512) {
    wT_tile(W1, w1t, 512, 1024, 512, 1024, b % 32, b / 32, tile);
  } else if (b < 1024) {
    int t = b - 512;  wT_tile(W2, w2t, 1024, 512, 1024, 512, t % 16, t / 16, tile);
  } else if (b < 1088) {
    int t = b - 1024; wT_tile(W3, w3t, 512, 128, 512, 128, t % 4, t / 4, tile);
  } else if (b < 1120) {
    int t = b - 1088; wT_tile(Wd1, wd1t, 128, 152, 128, 256, t % 8, t / 8, tile);
  } else if (b < 1152) {
    int t = b - 1120; wT_tile(Wd2, wd2t, 152, 48, 256, 128, t % 4, t / 4, tile);
  } else if (b < 11152) {
    int idx = ((b - 1152) * 256 + tid) * 4;
    if (idx < 20000 * 512) {
      float4 v = *reinterpret_cast<const float4*>(&x[idx]);
      uint2 o;
      o.x = cvt_pk_bf16(v.x, v.y);
      o.y = cvt_pk_bf16(v.z, v.w);
      *reinterpret_cast<uint2*>(&xb[idx]) = o;
    }
  } else if (b == 11152) {
    bd1p[tid] = (tid < 152) ? bd1[tid] : 0.f;
  } else if (b == 11153) {
    if (tid < 128) bd2p[tid] = (tid < 48) ? bd2[tid] : 0.f;
  } else if (b < 12404) {
    int e = (b - 11154) * 256 + tid;
    if (e < 320000) atomicAdd(&cnt1[dst[e]], 1);
  } else {
    int i = (b - 12404) * 256 + tid;
    if (i < 20000) cnt2[i] = 0;
  }
}

// ----------------------- CSR scan + scatter --------------------------------

__global__ __launch_bounds__(1024) void exscan_kernel(
    const int* __restrict__ in, int* __restrict__ out, int n) {
  __shared__ int wsum[16];
  __shared__ int carry_s;
  if (threadIdx.x == 0) carry_s = 0;
  __syncthreads();
  const int lane = threadIdx.x & 63, wv = threadIdx.x >> 6;
  for (int base = 0; base < n; base += 1024) {
    int i = base + threadIdx.x;
    int v = (i < n) ? in[i] : 0;
    int s = v;
    #pragma unroll
    for (int off = 1; off < 64; off <<= 1) {
      int t = __shfl_up(s, off, 64);
      if (lane >= off) s += t;
    }
    if (lane == 63) wsum[wv] = s;
    __syncthreads();
    if (wv == 0 && lane < 16) {
      int t = wsum[lane];
      #pragma unroll
      for (int off = 1; off < 16; off <<= 1) {
        int u = __shfl_up(t, off, 64);
        if (lane >= off) t += u;
      }
      wsum[lane] = t;
    }
    __syncthreads();
    int waveoff = (wv == 0) ? 0 : wsum[wv - 1];
    int res = carry_s + waveoff + s - v;
    if (i < n) out[i] = res;
    __syncthreads();
    if (threadIdx.x == 0) carry_s += wsum[15];
    __syncthreads();
  }
  if (threadIdx.x == 0) out[n] = carry_s;
}

__global__ __launch_bounds__(256) void scatter_csr(
    const int* __restrict__ dst, const int* __restrict__ src,
    const float* __restrict__ ew, const int* __restrict__ row_ptr,
    int* __restrict__ cnt, int* __restrict__ csr_src,
    float* __restrict__ csr_w, int E) {
  int e = blockIdx.x * 256 + threadIdx.x;
  if (e >= E) return;
  int d = dst[e];
  int pos = row_ptr[d] + atomicAdd(&cnt[d], 1);
  csr_src[pos] = src[e];
  csr_w[pos] = ew[e];
}

// ----------------------- 256x256 8-phase MFMA GEMM --------------------------
// C[M x Nn](bf16) = A[M x K] @ B, BT[Nn x K] given (bf16 row-major).
// M,Nn multiples of 256, K multiple of 64, nk = K/64 >= 4 and even.
// LDS: [P][A|B][ks][256][32] u16 (8 regions x 16KB = 128KB).
// Region staged = 2 x global_load_lds(16B) per thread (512 thr).
// Stage slot at phase p targets the region freed after phase p-1.
// Gates: per-wave counted vmcnt(10) at odd-phase ends (steady);
// final iteration (8,4,0). Prologue = 14 loads, order pinned by cfence().
template <int ACT, bool BIAS>
__global__ __launch_bounds__(512) void gemm_mfma_8ph(
    const u16* __restrict__ A, const u16* __restrict__ BT,
    const float* __restrict__ bias, u16* __restrict__ C,
    int K, int Nn) {
  __shared__ __align__(16) u16 LDS[65536];
  const int tid = threadIdx.x;
  const int lane = tid & 63;
  const int wave = tid >> 6;          // 0..7
  const int lo = lane & 15, hi = lane >> 4;
  const int wr = wave >> 2;           // 0..1
  const int wc = wave & 3;            // 0..3

  // bijective XCD swizzle (m204)
  const int gx = gridDim.x;
  const int nwg = gx * gridDim.y;
  const int wg = blockIdx.y * gx + blockIdx.x;
  const int q = nwg >> 3, r = nwg & 7;
  const int xcd = wg & 7, sidx = wg >> 3;
  const int swzb = (xcd < r ? xcd * (q + 1) : r * (q + 1) + (xcd - r) * q) + sidx;
  const int row0 = (swzb / gx) * 256;
  const int col0 = (swzb % gx) * 256;

  // ds_read element offsets within a [256][32] region, bank-swizzled
  int offA[8], offB[4];
  #pragma unroll
  for (int mf = 0; mf < 8; ++mf) {
    int row = wr * 128 + mf * 16 + lo;
    offA[mf] = row * 32 + (hi ^ ((row >> 1) & 3)) * 8;
  }
  #pragma unroll
  for (int nf = 0; nf < 4; ++nf) {
    int row = wc * 64 + nf * 16 + lo;
    offB[nf] = row * 32 + (hi ^ ((row >> 1) & 3)) * 8;
  }

  // stage source addressing: thread covers (row = p*128 + tid/4, slot = tid&3)
  // logical col = (slot ^ ((row>>1)&3))*8  == ((tid&3) ^ ((tid>>3)&3))*8
  const int r0 = tid >> 2;
  const int ce = ((tid & 3) ^ ((tid >> 3) & 3)) * 8;
  const u16* baseA = A + (size_t)(row0 + r0) * K + ce;
  const u16* baseB = BT + (size_t)(col0 + r0) * K + ce;
  const size_t rk128 = (size_t)128 * K;
  const int lb0 = tid * 8;            // elems

  f32x4 acc[8][4] = {};
  bf16x8 bfr[4];

  auto STAGE = [&](int mat, int P, int ks, int kt) {
    const u16* g = (mat ? baseB : baseA) + kt * 64 + ks * 32;
    int lb = P * 32768 + mat * 16384 + ks * 8192 + lb0;
    __builtin_amdgcn_global_load_lds((const AS1 void*)g,
                                     (AS3 void*)&LDS[lb], 16, 0, 0);
    __builtin_amdgcn_global_load_lds((const AS1 void*)(g + rk128),
                                     (AS3 void*)&LDS[lb + 4096], 16, 0, 0);
  };

  // phase: reads -> stage -> bar -> MFMA(16) -> [gate] -> bar
  auto PH = [&](int P, int ks, int mh, int stMat, int stP, int stKs, int stT,
                int gate) {
    bf16x8 af[4];
    if (mh == 0) {
      int rb = P * 32768 + 16384 + ks * 8192;
      #pragma unroll
      for (int nf = 0; nf < 4; ++nf)
        bfr[nf] = *reinterpret_cast<const bf16x8*>(&LDS[rb + offB[nf]]);
    }
    int ra = P * 32768 + ks * 8192;
    #pragma unroll
    for (int mf = 0; mf < 4; ++mf)
      af[mf] = *reinterpret_cast<const bf16x8*>(&LDS[ra + offA[mh * 4 + mf]]);
    if (stMat < 2) STAGE(stMat, stP, stKs, stT);
    __builtin_amdgcn_s_barrier();
    cfence();
    __builtin_amdgcn_s_setprio(1);
    #pragma unroll
    for (int mf = 0; mf < 4; ++mf)
      #pragma unroll
      for (int nf = 0; nf < 4; ++nf)
        acc[mh * 4 + mf][nf] = __builtin_amdgcn_mfma_f32_16x16x32_bf16(
            af[mf], bfr[nf], acc[mh * 4 + mf][nf], 0, 0, 0);
    __builtin_amdgcn_s_setprio(0);
    if (gate == 10) vmw<10>();
    else if (gate == 8) vmw<8>();
    else if (gate == 4) vmw<4>();
    else if (gate == 0) vmw<0>();
    __builtin_amdgcn_s_barrier();
    cfence();
  };

  // prologue: t0{B0,A0,B1,A1} + t1{B0,A0,B1}  (t1.A1 staged at iter0 ph0)
  STAGE(1, 0, 0, 0); cfence();
  STAGE(0, 0, 0, 0); cfence();
  STAGE(1, 0, 1, 0); cfence();
  STAGE(0, 0, 1, 0); cfence();
  STAGE(1, 1, 0, 1); cfence();
  STAGE(0, 1, 0, 1); cfence();
  STAGE(1, 1, 1, 1); cfence();
  vmw<10>();
  __builtin_amdgcn_s_barrier();
  cfence();

  const int nk = K >> 6;
  for (int kt = 0; kt + 2 < nk; kt += 2) {
    PH(0, 0, 0,  0, 1, 1, kt + 1, -1);   // ph0: stage (t+1).A-ks1 -> P1
    PH(0, 0, 1,  1, 0, 0, kt + 2, 10);   // ph1: stage (t+2).B-ks0 -> P0
    PH(0, 1, 0,  0, 0, 0, kt + 2, -1);   // ph2: stage (t+2).A-ks0 -> P0
    PH(0, 1, 1,  1, 0, 1, kt + 2, 10);   // ph3: stage (t+2).B-ks1 -> P0
    PH(1, 0, 0,  0, 0, 1, kt + 2, -1);   // ph4: stage (t+2).A-ks1 -> P0
    PH(1, 0, 1,  1, 1, 0, kt + 3, 10);   // ph5: stage (t+3).B-ks0 -> P1
    PH(1, 1, 0,  0, 1, 0, kt + 3, -1);   // ph6: stage (t+3).A-ks0 -> P1
    PH(1, 1, 1,  1, 1, 1, kt + 3, 10);   // ph7: stage (t+3).B-ks1 -> P1
  }
  {
    int kt = nk - 2;                     // final iteration
    PH(0, 0, 0,  0, 1, 1, kt + 1, -1);   // still stages (nk-1).A-ks1
    PH(0, 0, 1,  2, 0, 0, 0, 8);
    PH(0, 1, 0,  2, 0, 0, 0, -1);
    PH(0, 1, 1,  2, 0, 0, 0, 4);
    PH(1, 0, 0,  2, 0, 0, 0, -1);
    PH(1, 0, 1,  2, 0, 0, 0, 0);
    PH(1, 1, 0,  2, 0, 0, 0, -1);
    PH(1, 1, 1,  2, 0, 0, 0, -1);
  }

  float bv[4];
  if (BIAS) {
    #pragma unroll
    for (int nf = 0; nf < 4; ++nf) bv[nf] = bias[col0 + wc * 64 + nf * 16 + lo];
  }
  #pragma unroll
  for (int mf = 0; mf < 8; ++mf) {
    int rbase = row0 + wr * 128 + mf * 16 + hi * 4;
    #pragma unroll
    for (int nf = 0; nf < 4; ++nf) {
      int c = col0 + wc * 64 + nf * 16 + lo;
      float vv[4];
      #pragma unroll
      for (int i = 0; i < 4; ++i) {
        float v = acc[mf][nf][i];
        if (BIAS) v += bv[nf];
        if (ACT == 1) v = tanhf(v);
        else if (ACT == 2) v = fmaxf(v, 0.f);
        vv[i] = v;
      }
      unsigned int r01 = cvt_pk_bf16(vv[0], vv[1]);
      unsigned int r23 = cvt_pk_bf16(vv[2], vv[3]);
      u16* p = C + (size_t)rbase * Nn + c;
      p[0] = (u16)r01;
      p[Nn] = (u16)(r01 >> 16);
      p[2 * (size_t)Nn] = (u16)r23;
      p[3 * (size_t)Nn] = (u16)(r23 >> 16);
    }
  }
}

// ----------------------- 128x128 2-phase MFMA GEMM (small GEMMs) ------------
template <int ACT, bool BIAS, bool OUT_BF16>
__global__ __launch_bounds__(256) void gemm_mfma_db(
    const u16* __restrict__ A, const u16* __restrict__ BT,
    const float* __restrict__ bias, void* __restrict__ C,
    int M, int K, int Nn) {
  __shared__ __align__(16) u16 As[2][128 * 64];
  __shared__ __align__(16) u16 Bs[2][128 * 64];
  const int tid = threadIdx.x;
  const int lane = tid & 63;
  const int wave = tid >> 6;
  const int lo = lane & 15, hi = lane >> 4;
  const int wr = wave >> 1, wc = wave & 1;

  const int gx = gridDim.x;
  const int nwg = gx * gridDim.y;
  const int wg = blockIdx.y * gx + blockIdx.x;
  const int q = nwg >> 3, r = nwg & 7;
  const int xcd = wg & 7, sidx = wg >> 3;
  const int swz = (xcd < r ? xcd * (q + 1) : r * (q + 1) + (xcd - r) * q) + sidx;
  const int row0 = (swz / gx) * 128;
  const int col0 = (swz % gx) * 128;

  const u16* pa[4];
  const u16* pb[4];
  int so[4];
  #pragma unroll
  for (int i = 0; i < 4; ++i) {
    int o = i * 4096 + tid * 16;
    int rr = o >> 7;
    int ke = ((o & 127) >> 1) ^ ((rr & 7) << 3);
    pa[i] = &A[(size_t)(row0 + rr) * K + ke];
    pb[i] = &BT[(size_t)(col0 + rr) * K + ke];
    so[i] = o >> 1;
  }

  const int nk = K >> 6;
  f32x4 acc[4][4] = {};

  auto STAGE = [&](int buf, int kt) {
    const int ko = kt << 6;
    #pragma unroll
    for (int i = 0; i < 4; ++i) {
      __builtin_amdgcn_global_load_lds(
          (const AS1 void*)(pa[i] + ko),
          (AS3 void*)&As[buf][so[i]], 16, 0, 0);
      __builtin_amdgcn_global_load_lds(
          (const AS1 void*)(pb[i] + ko),
          (AS3 void*)&Bs[buf][so[i]], 16, 0, 0);
    }
  };

  STAGE(0, 0);
  STAGE(1, 1);
  asm volatile("s_waitcnt vmcnt(8)" ::: "memory");
  __builtin_amdgcn_s_barrier();

  auto body = [&](int cur, int kt) {
    bf16x8 af[2][4], bfr[2][4];
    #pragma unroll
    for (int ks = 0; ks < 2; ++ks) {
      #pragma unroll
      for (int m = 0; m < 4; ++m) {
        int row = wr * 64 + m * 16 + lo;
        int idx = (row * 64 + ks * 32 + hi * 8) ^ ((row & 7) << 3);
        af[ks][m] = *reinterpret_cast<const bf16x8*>(&As[cur][idx]);
      }
      #pragma unroll
      for (int n = 0; n < 4; ++n) {
        int col = wc * 64 + n * 16 + lo;
        int idx = (col * 64 + ks * 32 + hi * 8) ^ ((col & 7) << 3);
        bfr[ks][n] = *reinterpret_cast<const bf16x8*>(&Bs[cur][idx]);
      }
    }
    __builtin_amdgcn_s_setprio(1);
    #pragma unroll
    for (int ks = 0; ks < 2; ++ks)
      #pragma unroll
      for (int m = 0; m < 4; ++m)
        #pragma unroll
        for (int n = 0; n < 4; ++n)
          acc[m][n] = __builtin_amdgcn_mfma_f32_16x16x32_bf16(
              af[ks][m], bfr[ks][n], acc[m][n], 0, 0, 0);
    __builtin_amdgcn_s_setprio(0);
    asm volatile("s_waitcnt lgkmcnt(0)" ::: "memory");
    __builtin_amdgcn_s_barrier();
    if (kt + 2 < nk) {
      STAGE(cur, kt + 2);
      asm volatile("s_waitcnt vmcnt(8)" ::: "memory");
    } else if (kt + 1 < nk) {
      asm volatile("s_waitcnt vmcnt(0)" ::: "memory");
    }
    __builtin_amdgcn_s_barrier();
  };

  for (int kt = 0; kt < nk; kt += 2) {
    body(0, kt);
    body(1, kt + 1);
  }

  float bv[4];
  if (BIAS) {
    #pragma unroll
    for (int n = 0; n < 4; ++n) bv[n] = bias[col0 + wc * 64 + n * 16 + lo];
  }

  u16* Cb = (u16*)C;
  float* Cf = (float*)C;
  #pragma unroll
  for (int m = 0; m < 4; ++m) {
    int rbase = row0 + wr * 64 + m * 16 + hi * 4;
    #pragma unroll
    for (int n = 0; n < 4; ++n) {
      int c = col0 + wc * 64 + n * 16 + lo;
      float vv[4];
      #pragma unroll
      for (int i = 0; i < 4; ++i) {
        float v = acc[m][n][i];
        if (BIAS) v += bv[n];
        if (ACT == 1) v = tanhf(v);
        else if (ACT == 2) v = fmaxf(v, 0.f);
        vv[i] = v;
      }
      if (OUT_BF16) {
        unsigned int r01 = cvt_pk_bf16(vv[0], vv[1]);
        unsigned int r23 = cvt_pk_bf16(vv[2], vv[3]);
        u16* p = Cb + (size_t)rbase * Nn + c;
        p[0]              = (u16)r01;
        p[Nn]             = (u16)(r01 >> 16);
        p[2 * (size_t)Nn] = (u16)r23;
        p[3 * (size_t)Nn] = (u16)(r23 >> 16);
      } else {
        float* p = Cf + (size_t)rbase * Nn + c;
        p[0] = vv[0]; p[Nn] = vv[1];
        p[2 * (size_t)Nn] = vv[2]; p[3 * (size_t)Nn] = vv[3];
      }
    }
  }
}

// ----------------------- spmm: wave per node, F=512 -------------------------
template <int ACT, bool BIAS, bool OUT_BF16>
__global__ __launch_bounds__(256) void spmm_wave512(
    const int* __restrict__ row_ptr, const int* __restrict__ csr_src,
    const float* __restrict__ csr_w, const u16* __restrict__ H,
    const float* __restrict__ bias, void* __restrict__ out, int N) {
  __shared__ int s_src[4][64];
  __shared__ float s_w[4][64];
  const int wv = threadIdx.x >> 6;
  const int lane = threadIdx.x & 63;
  const int node = blockIdx.x * 4 + wv;
  if (node >= N) return;
  const int c = lane * 8;
  const int beg = row_ptr[node], end = row_ptr[node + 1];

  float a[8] = {};
  for (int p = beg; p < end; p += 64) {
    int cnt = end - p;
    if (cnt > 64) cnt = 64;
    if (lane < cnt) {
      s_src[wv][lane] = csr_src[p + lane];
      s_w[wv][lane] = csr_w[p + lane];
    }
    asm volatile("s_waitcnt lgkmcnt(0)" ::: "memory");
    int j = 0;
    for (; j + 3 < cnt; j += 4) {
      int s0 = s_src[wv][j], s1 = s_src[wv][j + 1];
      int s2 = s_src[wv][j + 2], s3 = s_src[wv][j + 3];
      float w0 = s_w[wv][j], w1 = s_w[wv][j + 1];
      float w2 = s_w[wv][j + 2], w3 = s_w[wv][j + 3];
      u16x8 h0 = *reinterpret_cast<const u16x8*>(&H[(size_t)s0 * 512 + c]);
      u16x8 h1 = *reinterpret_cast<const u16x8*>(&H[(size_t)s1 * 512 + c]);
      u16x8 h2 = *reinterpret_cast<const u16x8*>(&H[(size_t)s2 * 512 + c]);
      u16x8 h3 = *reinterpret_cast<const u16x8*>(&H[(size_t)s3 * 512 + c]);
      #pragma unroll
      for (int k = 0; k < 8; ++k)
        a[k] += w0 * b2f(h0[k]) + w1 * b2f(h1[k]) +
                w2 * b2f(h2[k]) + w3 * b2f(h3[k]);
    }
    for (; j < cnt; ++j) {
      int s = s_src[wv][j];
      float wt = s_w[wv][j];
      u16x8 hv = *reinterpret_cast<const u16x8*>(&H[(size_t)s * 512 + c]);
      #pragma unroll
      for (int k = 0; k < 8; ++k) a[k] += wt * b2f(hv[k]);
    }
    asm volatile("s_waitcnt lgkmcnt(0)" ::: "memory");
  }
  if (BIAS) {
    #pragma unroll
    for (int k = 0; k < 8; ++k) a[k] += bias[c + k];
  }
  if (ACT == 1) {
    #pragma unroll
    for (int k = 0; k < 8; ++k) a[k] = tanhf(a[k]);
  }
  if (OUT_BF16) {
    uint4 o;
    o.x = cvt_pk_bf16(a[0], a[1]);
    o.y = cvt_pk_bf16(a[2], a[3]);
    o.z = cvt_pk_bf16(a[4], a[5]);
    o.w = cvt_pk_bf16(a[6], a[7]);
    *reinterpret_cast<uint4*>(&((u16*)out)[(size_t)node * 512 + c]) = o;
  } else {
    float* op = &((float*)out)[(size_t)node * 512 + c];
    #pragma unroll
    for (int k = 0; k < 8; ++k) op[k] = a[k];
  }
}

// ----------------------- spmm: small F (128) --------------------------------
template <int F, int ACT, bool BIAS, bool OUT_BF16>
__global__ __launch_bounds__(256) void spmm_small(
    const int* __restrict__ row_ptr, const int* __restrict__ csr_src,
    const float* __restrict__ csr_w, const u16* __restrict__ H,
    const float* __restrict__ bias, void* __restrict__ out, int N) {
  constexpr int TPN = F / 8;
  constexpr int NPB = 256 / TPN;
  int sub = threadIdx.x / TPN;
  int ln = threadIdx.x - sub * TPN;
  int node = blockIdx.x * NPB + sub;
  if (node >= N) return;
  int c = ln * 8;
  int beg = row_ptr[node], end = row_ptr[node + 1];
  float a[8] = {};
  for (int p = beg; p < end; ++p) {
    int s = csr_src[p];
    float wt = csr_w[p];
    u16x8 hv = *reinterpret_cast<const u16x8*>(&H[(size_t)s * F + c]);
    #pragma unroll
    for (int k = 0; k < 8; ++k) a[k] += wt * b2f(hv[k]);
  }
  if (BIAS) {
    #pragma unroll
    for (int k = 0; k < 8; ++k) a[k] += bias[c + k];
  }
  if (ACT == 1) {
    #pragma unroll
    for (int k = 0; k < 8; ++k) a[k] = tanhf(a[k]);
  }
  if (OUT_BF16) {
    uint4 o;
    o.x = cvt_pk_bf16(a[0], a[1]);
    o.y = cvt_pk_bf16(a[2], a[3]);
    o.z = cvt_pk_bf16(a[4], a[5]);
    o.w = cvt_pk_bf16(a[6], a[7]);
    *reinterpret_cast<uint4*>(&((u16*)out)[(size_t)node * F + c]) = o;
  } else {
    float* op = &((float*)out)[(size_t)node * F + c];
    #pragma unroll
    for (int k = 0; k < 8; ++k) op[k] = a[k];
  }
}

// out[r] = dot(D2row(bf16)[:48], W[:48]) + b[0]
__global__ __launch_bounds__(256) void last_layer_bf16(
    const u16* __restrict__ D2v, const float* __restrict__ W,
    const float* __restrict__ b, float* __restrict__ out,
    int M, int K, int ld) {
  int rr = blockIdx.x * 256 + threadIdx.x;
  if (rr >= M) return;
  float s = b[0];
  const u16* row = &D2v[(size_t)rr * ld];
  #pragma unroll 8
  for (int k = 0; k < 48; ++k) s += b2f(row[k]) * W[k];
  out[rr] = s;
}

// ---------------------------------------------------------------------------

extern "C" void kernel_launch(void* const* d_in, const int* in_sizes, int n_in,
                              void* d_out, int out_size, void* d_ws, size_t ws_size,
                              hipStream_t stream) {
  const int N = 20000, E = 320000;
  const int F_IN = 512, H1 = 1024, H2 = 512, F_OUT = 128;
  const int D1P = 256, D2P = 128;

  const float* x    = (const float*)d_in[0];
  const int*   src  = (const int*)d_in[1];
  const int*   dst  = (const int*)d_in[2];
  const float* ew   = (const float*)d_in[3];
  const float* W1   = (const float*)d_in[4];
  const float* b1   = (const float*)d_in[5];
  const float* W2   = (const float*)d_in[6];
  const float* b2   = (const float*)d_in[7];
  const float* W3   = (const float*)d_in[8];
  const float* b3   = (const float*)d_in[9];
  const float* Wd1  = (const float*)d_in[10];
  const float* bd1  = (const float*)d_in[11];
  const float* Wd2  = (const float*)d_in[12];
  const float* bd2  = (const float*)d_in[13];
  const float* Wd3  = (const float*)d_in[14];
  const float* bd3  = (const float*)d_in[15];
  float* out = (float*)d_out;

  size_t off = 0;
  auto alloc = [&](size_t bytes) {
    void* p = (char*)d_ws + off;
    off += (bytes + 255) & ~(size_t)255;
    return p;
  };
  u16* xb   = (u16*)alloc((size_t)MPAD * F_IN * 2);    // x bf16; later t2
  u16* ax   = (u16*)alloc((size_t)MPAD * F_IN * 2);    // A@x;   later h2
  u16* h1   = (u16*)alloc((size_t)MPAD * H1 * 2);      // h1 (also t3..d2 region)
  u16* w1t  = (u16*)alloc((size_t)H1 * F_IN * 2);
  u16* w2t  = (u16*)alloc((size_t)H2 * H1 * 2);
  u16* w3t  = (u16*)alloc((size_t)F_OUT * H2 * 2);
  u16* wd1t = (u16*)alloc((size_t)D1P * F_OUT * 2);
  u16* wd2t = (u16*)alloc((size_t)D2P * D1P * 2);
  float* bd1p = (float*)alloc((size_t)D1P * 4);
  float* bd2p = (float*)alloc((size_t)D2P * 4);
  int* row_ptr = (int*)alloc((size_t)(N + 1) * 4);
  int* cnt1    = (int*)alloc((size_t)N * 4);
  int* cnt2    = (int*)alloc((size_t)N * 4);
  int* csr_src = (int*)alloc((size_t)E * 4);
  float* csr_w = (float*)alloc((size_t)E * 4);

  u16* t2 = xb;
  u16* h2 = ax;
  u16* t3 = h1;
  u16* gb = t3 + (size_t)MPAD * F_OUT;
  u16* d1 = gb + (size_t)MPAD * F_OUT;
  u16* d2 = d1 + (size_t)MPAD * D1P;

  auto cdiv = [](int a, int b) { return (a + b - 1) / b; };

  // ---- prep ----
  hipMemsetAsync(cnt1, 0, (size_t)N * 4, stream);
  prep_all<<<12483, 256, 0, stream>>>(x, xb, W1, w1t, W2, w2t, W3, w3t,
                                      Wd1, wd1t, Wd2, wd2t, bd1, bd1p,
                                      bd2, bd2p, dst, cnt1, cnt2);
  exscan_kernel<<<1, 1024, 0, stream>>>(cnt1, row_ptr, N);
  scatter_csr<<<cdiv(E, 256), 256, 0, stream>>>(dst, src, ew, row_ptr, cnt2,
                                                csr_src, csr_w, E);

  // ---- layer 1 (reordered): ax = A@x ; h1 = tanh(ax@W1 + b1) ----
  spmm_wave512<0, false, true><<<cdiv(N, 4), 256, 0, stream>>>(
      row_ptr, csr_src, csr_w, xb, nullptr, ax, N);
  gemm_mfma_8ph<1, true><<<dim3(H1 / 256, MPAD / 256), 512, 0, stream>>>(
      ax, w1t, b1, h1, F_IN, H1);

  // ---- layer 2: t2 = h1@W2 ; h2 = tanh(A@t2 + b2) ----
  gemm_mfma_8ph<0, false><<<dim3(H2 / 256, MPAD / 256), 512, 0, stream>>>(
      h1, w2t, nullptr, t2, H1, H2);
  spmm_wave512<1, true, true><<<cdiv(N, 4), 256, 0, stream>>>(
      row_ptr, csr_src, csr_w, t2, b2, h2, N);

  // ---- layer 3: t3 = h2@W3 ; gb = A@t3 + b3 (bf16) ----
  gemm_mfma_db<0, false, true><<<dim3(F_OUT / 128, MPAD / 128), 256, 0, stream>>>(
      h2, w3t, nullptr, t3, MPAD, H2, F_OUT);
  spmm_small<128, 0, true, true><<<cdiv(N, 16), 256, 0, stream>>>(
      row_ptr, csr_src, csr_w, t3, b3, gb, N);

  // ---- dense head (bf16 MFMA, padded widths) ----
  gemm_mfma_db<2, true, true><<<dim3(D1P / 128, MPAD / 128), 256, 0, stream>>>(
      gb, wd1t, bd1p, d1, MPAD, F_OUT, D1P);
  gemm_mfma_db<2, true, true><<<dim3(D2P / 128, MPAD / 128), 256, 0, stream>>>(
      d1, wd2t, bd2p, d2, MPAD, D1P, D2P);
  last_layer_bf16<<<cdiv(N, 256), 256, 0, stream>>>(d2, Wd3, bd3, out, N, 48, D2P);
}

// Round 10
// 251.975 us; speedup vs baseline: 1.1779x; 1.1779x over previous
//
#include <hip/hip_runtime.h>
#include <hip/hip_bf16.h>

// ---------------------------------------------------------------------------
// GCN (3x GCNConv) + dense head, bf16 MFMA.
// Round 10: revert to R8 128x128 2-phase GEMM (256x256 8-phase was
// grid-starved at N=512/1024: 158-316 blocks on 256 CUs). Additions:
// fast exp-based tanh (8 ops vs ~25), spmm unroll-8, two-level exscan.
// ---------------------------------------------------------------------------

typedef __attribute__((ext_vector_type(8))) short bf16x8;
typedef __attribute__((ext_vector_type(8))) unsigned short u16x8;
typedef __attribute__((ext_vector_type(4))) float f32x4;
typedef unsigned short u16;

#define MPAD 20096   // 157 * 128
#define AS1 __attribute__((address_space(1)))
#define AS3 __attribute__((address_space(3)))

__device__ inline u16 f2b(float f) {
  union { float f; unsigned int u; } x; x.f = f;
  unsigned int r = x.u + 0x7FFFu + ((x.u >> 16) & 1u);   // RNE
  return (u16)(r >> 16);
}
__device__ inline float b2f(u16 u) {
  union { unsigned int u; float f; } x; x.u = ((unsigned int)u) << 16; return x.f;
}
__device__ inline unsigned int cvt_pk_bf16(float lo, float hi) {
  unsigned int r;
  asm("v_cvt_pk_bf16_f32 %0, %1, %2" : "=v"(r) : "v"(lo), "v"(hi));
  return r;
}
// tanh(x) = (e^2x - 1)/(e^2x + 1); clamp so e^2x can't overflow.
// ~1e-7 rel err, far below bf16 rounding. 2 transcendentals vs tanhf's ~25 ops.
__device__ inline float fast_tanh(float x) {
  float cx = fminf(fmaxf(x, -9.f), 9.f);
  float e = __expf(2.f * cx);
  float d = e + 1.f, r;
  asm("v_rcp_f32 %0, %1" : "=v"(r) : "v"(d));
  return (e - 1.f) * r;
}

// ----------------------- fused prep kernel ---------------------------------

__device__ inline void wT_tile(const float* __restrict__ W, u16* __restrict__ WT,
                               int K, int N, int KPAD, int NPAD,
                               int bx, int by, float (*tile)[33]) {
  const int kb = by * 32, nb = bx * 32;
  const int tx = threadIdx.x & 31, ty = threadIdx.x >> 5;
  #pragma unroll
  for (int i = 0; i < 4; ++i) {
    int k = kb + ty + i * 8, n = nb + tx;
    tile[ty + i * 8][tx] = (k < K && n < N) ? W[(size_t)k * N + n] : 0.f;
  }
  __syncthreads();
  #pragma unroll
  for (int i = 0; i < 4; ++i) {
    int n = nb + ty + i * 8, k = kb + tx;
    WT[(size_t)n * KPAD + k] = f2b(tile[tx][ty + i * 8]);
  }
}

__global__ __launch_bounds__(256) void prep_all(
    const float* __restrict__ x, u16* __restrict__ xb,
    const float* __restrict__ W1, u16* __restrict__ w1t,
    const float* __restrict__ W2, u16* __restrict__ w2t,
    const float* __restrict__ W3, u16* __restrict__ w3t,
    const float* __restrict__ Wd1, u16* __restrict__ wd1t,
    const float* __restrict__ Wd2, u16* __restrict__ wd2t,
    const float* __restrict__ bd1, float* __restrict__ bd1p,
    const float* __restrict__ bd2, float* __restrict__ bd2p,
    const int* __restrict__ dst, int* __restrict__ cnt1,
    int* __restrict__ cnt2) {
  __shared__ float tile[32][33];
  const int b = blockIdx.x;
  const int tid = threadIdx.x;
  if (b < 512) {
    wT_tile(W1, w1t, 512, 1024, 512, 1024, b % 32, b / 32, tile);
  } else if (b < 1024) {
    int t = b - 512;  wT_tile(W2, w2t, 1024, 512, 1024, 512, t % 16, t / 16, tile);
  } else if (b < 1088) {
    int t = b - 1024; wT_tile(W3, w3t, 512, 128, 512, 128, t % 4, t / 4, tile);
  } else if (b < 1120) {
    int t = b - 1088; wT_tile(Wd1, wd1t, 128, 152, 128, 256, t % 8, t / 8, tile);
  } else if (b < 1152) {
    int t = b - 1120; wT_tile(Wd2, wd2t, 152, 48, 256, 128, t % 4, t / 4, tile);
  } else if (b < 11152) {
    int idx = ((b - 1152) * 256 + tid) * 4;
    if (idx < 20000 * 512) {
      float4 v = *reinterpret_cast<const float4*>(&x[idx]);
      uint2 o;
      o.x = cvt_pk_bf16(v.x, v.y);
      o.y = cvt_pk_bf16(v.z, v.w);
      *reinterpret_cast<uint2*>(&xb[idx]) = o;
    }
  } else if (b == 11152) {
    bd1p[tid] = (tid < 152) ? bd1[tid] : 0.f;
  } else if (b == 11153) {
    if (tid < 128) bd2p[tid] = (tid < 48) ? bd2[tid] : 0.f;
  } else if (b < 12404) {
    int e = (b - 11154) * 256 + tid;
    if (e < 320000) atomicAdd(&cnt1[dst[e]], 1);
  } else {
    int i = (b - 12404) * 256 + tid;
    if (i < 20000) cnt2[i] = 0;
  }
}

// ----------------------- two-level exclusive scan --------------------------
// pass 1: 20 blocks x 1024, per-block exclusive scan + block sums
__global__ __launch_bounds__(1024) void scan_part(
    const int* __restrict__ in, int* __restrict__ out,
    int* __restrict__ bsum, int n) {
  __shared__ int wsum[16];
  const int lane = threadIdx.x & 63, wv = threadIdx.x >> 6;
  int i = blockIdx.x * 1024 + threadIdx.x;
  int v = (i < n) ? in[i] : 0;
  int s = v;
  #pragma unroll
  for (int off = 1; off < 64; off <<= 1) {
    int t = __shfl_up(s, off, 64);
    if (lane >= off) s += t;
  }
  if (lane == 63) wsum[wv] = s;
  __syncthreads();
  if (wv == 0 && lane < 16) {
    int t = wsum[lane];
    #pragma unroll
    for (int off = 1; off < 16; off <<= 1) {
      int u = __shfl_up(t, off, 64);
      if (lane >= off) t += u;
    }
    wsum[lane] = t;
  }
  __syncthreads();
  int waveoff = (wv == 0) ? 0 : wsum[wv - 1];
  if (i < n) out[i] = waveoff + s - v;
  if (threadIdx.x == 0) bsum[blockIdx.x] = wsum[15];
}
// pass 2: add block-prefix; write out[n] = total
__global__ __launch_bounds__(1024) void scan_fix(
    int* __restrict__ out, const int* __restrict__ bsum, int n, int nb) {
  int b = blockIdx.x;
  int pre = 0, tot = 0;
  for (int j = 0; j < nb; ++j) {
    int v = bsum[j];
    if (j < b) pre += v;
    tot += v;
  }
  int i = b * 1024 + threadIdx.x;
  if (i < n && b > 0) out[i] += pre;
  if (b == 0 && threadIdx.x == 0) out[n] = tot;
}

__global__ __launch_bounds__(256) void scatter_csr(
    const int* __restrict__ dst, const int* __restrict__ src,
    const float* __restrict__ ew, const int* __restrict__ row_ptr,
    int* __restrict__ cnt, int* __restrict__ csr_src,
    float* __restrict__ csr_w, int E) {
  int e = blockIdx.x * 256 + threadIdx.x;
  if (e >= E) return;
  int d = dst[e];
  int pos = row_ptr[d] + atomicAdd(&cnt[d], 1);
  csr_src[pos] = src[e];
  csr_w[pos] = ew[e];
}

// ----------------------- 128x128 2-phase MFMA GEMM (R8-proven) --------------
template <int ACT, bool BIAS, bool OUT_BF16>
__global__ __launch_bounds__(256) void gemm_mfma_db(
    const u16* __restrict__ A, const u16* __restrict__ BT,
    const float* __restrict__ bias, void* __restrict__ C,
    int M, int K, int Nn) {
  __shared__ __align__(16) u16 As[2][128 * 64];
  __shared__ __align__(16) u16 Bs[2][128 * 64];
  const int tid = threadIdx.x;
  const int lane = tid & 63;
  const int wave = tid >> 6;
  const int lo = lane & 15, hi = lane >> 4;
  const int wr = wave >> 1, wc = wave & 1;

  const int gx = gridDim.x;
  const int nwg = gx * gridDim.y;
  const int wg = blockIdx.y * gx + blockIdx.x;
  const int q = nwg >> 3, r = nwg & 7;
  const int xcd = wg & 7, sidx = wg >> 3;
  const int swz = (xcd < r ? xcd * (q + 1) : r * (q + 1) + (xcd - r) * q) + sidx;
  const int row0 = (swz / gx) * 128;
  const int col0 = (swz % gx) * 128;

  const u16* pa[4];
  const u16* pb[4];
  int so[4];
  #pragma unroll
  for (int i = 0; i < 4; ++i) {
    int o = i * 4096 + tid * 16;
    int rr = o >> 7;
    int ke = ((o & 127) >> 1) ^ ((rr & 7) << 3);
    pa[i] = &A[(size_t)(row0 + rr) * K + ke];
    pb[i] = &BT[(size_t)(col0 + rr) * K + ke];
    so[i] = o >> 1;
  }

  const int nk = K >> 6;
  f32x4 acc[4][4] = {};

  auto STAGE = [&](int buf, int kt) {
    const int ko = kt << 6;
    #pragma unroll
    for (int i = 0; i < 4; ++i) {
      __builtin_amdgcn_global_load_lds(
          (const AS1 void*)(pa[i] + ko),
          (AS3 void*)&As[buf][so[i]], 16, 0, 0);
      __builtin_amdgcn_global_load_lds(
          (const AS1 void*)(pb[i] + ko),
          (AS3 void*)&Bs[buf][so[i]], 16, 0, 0);
    }
  };

  STAGE(0, 0);
  STAGE(1, 1);
  asm volatile("s_waitcnt vmcnt(8)" ::: "memory");
  __builtin_amdgcn_s_barrier();

  auto body = [&](int cur, int kt) {
    bf16x8 af[2][4], bfr[2][4];
    #pragma unroll
    for (int ks = 0; ks < 2; ++ks) {
      #pragma unroll
      for (int m = 0; m < 4; ++m) {
        int row = wr * 64 + m * 16 + lo;
        int idx = (row * 64 + ks * 32 + hi * 8) ^ ((row & 7) << 3);
        af[ks][m] = *reinterpret_cast<const bf16x8*>(&As[cur][idx]);
      }
      #pragma unroll
      for (int n = 0; n < 4; ++n) {
        int col = wc * 64 + n * 16 + lo;
        int idx = (col * 64 + ks * 32 + hi * 8) ^ ((col & 7) << 3);
        bfr[ks][n] = *reinterpret_cast<const bf16x8*>(&Bs[cur][idx]);
      }
    }
    __builtin_amdgcn_s_setprio(1);
    #pragma unroll
    for (int ks = 0; ks < 2; ++ks)
      #pragma unroll
      for (int m = 0; m < 4; ++m)
        #pragma unroll
        for (int n = 0; n < 4; ++n)
          acc[m][n] = __builtin_amdgcn_mfma_f32_16x16x32_bf16(
              af[ks][m], bfr[ks][n], acc[m][n], 0, 0, 0);
    __builtin_amdgcn_s_setprio(0);
    asm volatile("s_waitcnt lgkmcnt(0)" ::: "memory");
    __builtin_amdgcn_s_barrier();
    if (kt + 2 < nk) {
      STAGE(cur, kt + 2);
      asm volatile("s_waitcnt vmcnt(8)" ::: "memory");
    } else if (kt + 1 < nk) {
      asm volatile("s_waitcnt vmcnt(0)" ::: "memory");
    }
    __builtin_amdgcn_s_barrier();
  };

  for (int kt = 0; kt < nk; kt += 2) {   // all nk are even (2,4,8,16)
    body(0, kt);
    body(1, kt + 1);
  }

  float bv[4];
  if (BIAS) {
    #pragma unroll
    for (int n = 0; n < 4; ++n) bv[n] = bias[col0 + wc * 64 + n * 16 + lo];
  }

  u16* Cb = (u16*)C;
  float* Cf = (float*)C;
  #pragma unroll
  for (int m = 0; m < 4; ++m) {
    int rbase = row0 + wr * 64 + m * 16 + hi * 4;
    #pragma unroll
    for (int n = 0; n < 4; ++n) {
      int c = col0 + wc * 64 + n * 16 + lo;
      float vv[4];
      #pragma unroll
      for (int i = 0; i < 4; ++i) {
        float v = acc[m][n][i];
        if (BIAS) v += bv[n];
        if (ACT == 1) v = fast_tanh(v);
        else if (ACT == 2) v = fmaxf(v, 0.f);
        vv[i] = v;
      }
      if (OUT_BF16) {
        unsigned int r01 = cvt_pk_bf16(vv[0], vv[1]);
        unsigned int r23 = cvt_pk_bf16(vv[2], vv[3]);
        u16* p = Cb + (size_t)rbase * Nn + c;
        p[0]              = (u16)r01;
        p[Nn]             = (u16)(r01 >> 16);
        p[2 * (size_t)Nn] = (u16)r23;
        p[3 * (size_t)Nn] = (u16)(r23 >> 16);
      } else {
        float* p = Cf + (size_t)rbase * Nn + c;
        p[0] = vv[0]; p[Nn] = vv[1];
        p[2 * (size_t)Nn] = vv[2]; p[3 * (size_t)Nn] = vv[3];
      }
    }
  }
}

// ----------------------- spmm: wave per node, F=512 -------------------------
template <int ACT, bool BIAS, bool OUT_BF16>
__global__ __launch_bounds__(256) void spmm_wave512(
    const int* __restrict__ row_ptr, const int* __restrict__ csr_src,
    const float* __restrict__ csr_w, const u16* __restrict__ H,
    const float* __restrict__ bias, void* __restrict__ out, int N) {
  __shared__ int s_src[4][64];
  __shared__ float s_w[4][64];
  const int wv = threadIdx.x >> 6;
  const int lane = threadIdx.x & 63;
  const int node = blockIdx.x * 4 + wv;
  if (node >= N) return;
  const int c = lane * 8;
  const int beg = row_ptr[node], end = row_ptr[node + 1];

  float a[8] = {};
  for (int p = beg; p < end; p += 64) {
    int cnt = end - p;
    if (cnt > 64) cnt = 64;
    if (lane < cnt) {
      s_src[wv][lane] = csr_src[p + lane];
      s_w[wv][lane] = csr_w[p + lane];
    }
    asm volatile("s_waitcnt lgkmcnt(0)" ::: "memory");
    int j = 0;
    for (; j + 7 < cnt; j += 8) {       // 8 gathers in flight
      int ss[8]; float ww[8]; u16x8 hh[8];
      #pragma unroll
      for (int u = 0; u < 8; ++u) { ss[u] = s_src[wv][j + u]; ww[u] = s_w[wv][j + u]; }
      #pragma unroll
      for (int u = 0; u < 8; ++u)
        hh[u] = *reinterpret_cast<const u16x8*>(&H[(size_t)ss[u] * 512 + c]);
      #pragma unroll
      for (int u = 0; u < 8; ++u)
        #pragma unroll
        for (int k = 0; k < 8; ++k) a[k] += ww[u] * b2f(hh[u][k]);
    }
    for (; j < cnt; ++j) {
      int s = s_src[wv][j];
      float wt = s_w[wv][j];
      u16x8 hv = *reinterpret_cast<const u16x8*>(&H[(size_t)s * 512 + c]);
      #pragma unroll
      for (int k = 0; k < 8; ++k) a[k] += wt * b2f(hv[k]);
    }
    asm volatile("s_waitcnt lgkmcnt(0)" ::: "memory");
  }
  if (BIAS) {
    #pragma unroll
    for (int k = 0; k < 8; ++k) a[k] += bias[c + k];
  }
  if (ACT == 1) {
    #pragma unroll
    for (int k = 0; k < 8; ++k) a[k] = fast_tanh(a[k]);
  }
  if (OUT_BF16) {
    uint4 o;
    o.x = cvt_pk_bf16(a[0], a[1]);
    o.y = cvt_pk_bf16(a[2], a[3]);
    o.z = cvt_pk_bf16(a[4], a[5]);
    o.w = cvt_pk_bf16(a[6], a[7]);
    *reinterpret_cast<uint4*>(&((u16*)out)[(size_t)node * 512 + c]) = o;
  } else {
    float* op = &((float*)out)[(size_t)node * 512 + c];
    #pragma unroll
    for (int k = 0; k < 8; ++k) op[k] = a[k];
  }
}

// ----------------------- spmm: small F (128) --------------------------------
template <int F, int ACT, bool BIAS, bool OUT_BF16>
__global__ __launch_bounds__(256) void spmm_small(
    const int* __restrict__ row_ptr, const int* __restrict__ csr_src,
    const float* __restrict__ csr_w, const u16* __restrict__ H,
    const float* __restrict__ bias, void* __restrict__ out, int N) {
  constexpr int TPN = F / 8;
  constexpr int NPB = 256 / TPN;
  int sub = threadIdx.x / TPN;
  int ln = threadIdx.x - sub * TPN;
  int node = blockIdx.x * NPB + sub;
  if (node >= N) return;
  int c = ln * 8;
  int beg = row_ptr[node], end = row_ptr[node + 1];
  float a[8] = {};
  int p = beg;
  for (; p + 3 < end; p += 4) {
    int s0 = csr_src[p], s1 = csr_src[p + 1], s2 = csr_src[p + 2], s3 = csr_src[p + 3];
    float w0 = csr_w[p], w1 = csr_w[p + 1], w2 = csr_w[p + 2], w3 = csr_w[p + 3];
    u16x8 h0 = *reinterpret_cast<const u16x8*>(&H[(size_t)s0 * F + c]);
    u16x8 h1 = *reinterpret_cast<const u16x8*>(&H[(size_t)s1 * F + c]);
    u16x8 h2 = *reinterpret_cast<const u16x8*>(&H[(size_t)s2 * F + c]);
    u16x8 h3 = *reinterpret_cast<const u16x8*>(&H[(size_t)s3 * F + c]);
    #pragma unroll
    for (int k = 0; k < 8; ++k)
      a[k] += w0 * b2f(h0[k]) + w1 * b2f(h1[k]) +
              w2 * b2f(h2[k]) + w3 * b2f(h3[k]);
  }
  for (; p < end; ++p) {
    int s = csr_src[p];
    float wt = csr_w[p];
    u16x8 hv = *reinterpret_cast<const u16x8*>(&H[(size_t)s * F + c]);
    #pragma unroll
    for (int k = 0; k < 8; ++k) a[k] += wt * b2f(hv[k]);
  }
  if (BIAS) {
    #pragma unroll
    for (int k = 0; k < 8; ++k) a[k] += bias[c + k];
  }
  if (ACT == 1) {
    #pragma unroll
    for (int k = 0; k < 8; ++k) a[k] = fast_tanh(a[k]);
  }
  if (OUT_BF16) {
    uint4 o;
    o.x = cvt_pk_bf16(a[0], a[1]);
    o.y = cvt_pk_bf16(a[2], a[3]);
    o.z = cvt_pk_bf16(a[4], a[5]);
    o.w = cvt_pk_bf16(a[6], a[7]);
    *reinterpret_cast<uint4*>(&((u16*)out)[(size_t)node * F + c]) = o;
  } else {
    float* op = &((float*)out)[(size_t)node * F + c];
    #pragma unroll
    for (int k = 0; k < 8; ++k) op[k] = a[k];
  }
}

// out[r] = dot(D2row(bf16)[:48], W[:48]) + b[0]
__global__ __launch_bounds__(256) void last_layer_bf16(
    const u16* __restrict__ D2v, const float* __restrict__ W,
    const float* __restrict__ b, float* __restrict__ out,
    int M, int K, int ld) {
  int rr = blockIdx.x * 256 + threadIdx.x;
  if (rr >= M) return;
  float s = b[0];
  const u16* row = &D2v[(size_t)rr * ld];
  #pragma unroll 8
  for (int k = 0; k < 48; ++k) s += b2f(row[k]) * W[k];
  out[rr] = s;
}

// ---------------------------------------------------------------------------

extern "C" void kernel_launch(void* const* d_in, const int* in_sizes, int n_in,
                              void* d_out, int out_size, void* d_ws, size_t ws_size,
                              hipStream_t stream) {
  const int N = 20000, E = 320000;
  const int F_IN = 512, H1 = 1024, H2 = 512, F_OUT = 128;
  const int D1P = 256, D2P = 128;

  const float* x    = (const float*)d_in[0];
  const int*   src  = (const int*)d_in[1];
  const int*   dst  = (const int*)d_in[2];
  const float* ew   = (const float*)d_in[3];
  const float* W1   = (const float*)d_in[4];
  const float* b1   = (const float*)d_in[5];
  const float* W2   = (const float*)d_in[6];
  const float* b2   = (const float*)d_in[7];
  const float* W3   = (const float*)d_in[8];
  const float* b3   = (const float*)d_in[9];
  const float* Wd1  = (const float*)d_in[10];
  const float* bd1  = (const float*)d_in[11];
  const float* Wd2  = (const float*)d_in[12];
  const float* bd2  = (const float*)d_in[13];
  const float* Wd3  = (const float*)d_in[14];
  const float* bd3  = (const float*)d_in[15];
  float* out = (float*)d_out;

  size_t off = 0;
  auto alloc = [&](size_t bytes) {
    void* p = (char*)d_ws + off;
    off += (bytes + 255) & ~(size_t)255;
    return p;
  };
  u16* xb   = (u16*)alloc((size_t)MPAD * F_IN * 2);    // x bf16; later t2
  u16* ax   = (u16*)alloc((size_t)MPAD * F_IN * 2);    // A@x;   later h2
  u16* h1   = (u16*)alloc((size_t)MPAD * H1 * 2);      // h1 (also t3..d2 region)
  u16* w1t  = (u16*)alloc((size_t)H1 * F_IN * 2);
  u16* w2t  = (u16*)alloc((size_t)H2 * H1 * 2);
  u16* w3t  = (u16*)alloc((size_t)F_OUT * H2 * 2);
  u16* wd1t = (u16*)alloc((size_t)D1P * F_OUT * 2);
  u16* wd2t = (u16*)alloc((size_t)D2P * D1P * 2);
  float* bd1p = (float*)alloc((size_t)D1P * 4);
  float* bd2p = (float*)alloc((size_t)D2P * 4);
  int* row_ptr = (int*)alloc((size_t)(N + 1) * 4);
  int* cnt1    = (int*)alloc((size_t)N * 4);
  int* cnt2    = (int*)alloc((size_t)N * 4);
  int* bsum    = (int*)alloc((size_t)32 * 4);
  int* csr_src = (int*)alloc((size_t)E * 4);
  float* csr_w = (float*)alloc((size_t)E * 4);

  u16* t2 = xb;
  u16* h2 = ax;
  u16* t3 = h1;
  u16* gb = t3 + (size_t)MPAD * F_OUT;
  u16* d1 = gb + (size_t)MPAD * F_OUT;
  u16* d2 = d1 + (size_t)MPAD * D1P;

  auto cdiv = [](int a, int b) { return (a + b - 1) / b; };

  // ---- prep ----
  hipMemsetAsync(cnt1, 0, (size_t)N * 4, stream);
  prep_all<<<12483, 256, 0, stream>>>(x, xb, W1, w1t, W2, w2t, W3, w3t,
                                      Wd1, wd1t, Wd2, wd2t, bd1, bd1p,
                                      bd2, bd2p, dst, cnt1, cnt2);
  scan_part<<<20, 1024, 0, stream>>>(cnt1, row_ptr, bsum, N);
  scan_fix<<<20, 1024, 0, stream>>>(row_ptr, bsum, N, 20);
  scatter_csr<<<cdiv(E, 256), 256, 0, stream>>>(dst, src, ew, row_ptr, cnt2,
                                                csr_src, csr_w, E);

  // ---- layer 1 (reordered): ax = A@x ; h1 = tanh(ax@W1 + b1) ----
  spmm_wave512<0, false, true><<<cdiv(N, 4), 256, 0, stream>>>(
      row_ptr, csr_src, csr_w, xb, nullptr, ax, N);
  gemm_mfma_db<1, true, true><<<dim3(H1 / 128, MPAD / 128), 256, 0, stream>>>(
      ax, w1t, b1, h1, MPAD, F_IN, H1);

  // ---- layer 2: t2 = h1@W2 ; h2 = tanh(A@t2 + b2) ----
  gemm_mfma_db<0, false, true><<<dim3(H2 / 128, MPAD / 128), 256, 0, stream>>>(
      h1, w2t, nullptr, t2, MPAD, H1, H2);
  spmm_wave512<1, true, true><<<cdiv(N, 4), 256, 0, stream>>>(
      row_ptr, csr_src, csr_w, t2, b2, h2, N);

  // ---- layer 3: t3 = h2@W3 ; gb = A@t3 + b3 (bf16) ----
  gemm_mfma_db<0, false, true><<<dim3(F_OUT / 128, MPAD / 128), 256, 0, stream>>>(
      h2, w3t, nullptr, t3, MPAD, H2, F_OUT);
  spmm_small<128, 0, true, true><<<cdiv(N, 16), 256, 0, stream>>>(
      row_ptr, csr_src, csr_w, t3, b3, gb, N);

  // ---- dense head (bf16 MFMA, padded widths) ----
  gemm_mfma_db<2, true, true><<<dim3(D1P / 128, MPAD / 128), 256, 0, stream>>>(
      gb, wd1t, bd1p, d1, MPAD, F_OUT, D1P);
  gemm_mfma_db<2, true, true><<<dim3(D2P / 128, MPAD / 128), 256, 0, stream>>>(
      d1, wd2t, bd2p, d2, MPAD, D1P, D2P);
  last_layer_bf16<<<cdiv(N, 256), 256, 0, stream>>>(d2, Wd3, bd3, out, N, 48, D2P);
}

// Round 11
// 245.253 us; speedup vs baseline: 1.2101x; 1.0274x over previous
//
#include <hip/hip_runtime.h>
#include <hip/hip_bf16.h>

// ---------------------------------------------------------------------------
// GCN (3x GCNConv) + dense head, bf16 MFMA.
// Round 11: XCD-sharded spmm — each XCD owns a 64-column slice (2.56 MB
// < 4 MB per-XCD L2) via chunk = blockIdx % NCHUNKS pinning; packed
// (u16 src | bf16 w) edge records. Everything else = R10 (proven 252 us).
// ---------------------------------------------------------------------------

typedef __attribute__((ext_vector_type(8))) short bf16x8;
typedef __attribute__((ext_vector_type(8))) unsigned short u16x8;
typedef __attribute__((ext_vector_type(4))) float f32x4;
typedef unsigned short u16;

#define MPAD 20096   // 157 * 128
#define AS1 __attribute__((address_space(1)))
#define AS3 __attribute__((address_space(3)))

__device__ inline u16 f2b(float f) {
  union { float f; unsigned int u; } x; x.f = f;
  unsigned int r = x.u + 0x7FFFu + ((x.u >> 16) & 1u);   // RNE
  return (u16)(r >> 16);
}
__device__ inline float b2f(u16 u) {
  union { unsigned int u; float f; } x; x.u = ((unsigned int)u) << 16; return x.f;
}
__device__ inline unsigned int cvt_pk_bf16(float lo, float hi) {
  unsigned int r;
  asm("v_cvt_pk_bf16_f32 %0, %1, %2" : "=v"(r) : "v"(lo), "v"(hi));
  return r;
}
// tanh(x) = (e^2x - 1)/(e^2x + 1); clamped. ~1e-7 rel err.
__device__ inline float fast_tanh(float x) {
  float cx = fminf(fmaxf(x, -9.f), 9.f);
  float e = __expf(2.f * cx);
  float d = e + 1.f, r;
  asm("v_rcp_f32 %0, %1" : "=v"(r) : "v"(d));
  return (e - 1.f) * r;
}

// ----------------------- fused prep kernel ---------------------------------

__device__ inline void wT_tile(const float* __restrict__ W, u16* __restrict__ WT,
                               int K, int N, int KPAD, int NPAD,
                               int bx, int by, float (*tile)[33]) {
  const int kb = by * 32, nb = bx * 32;
  const int tx = threadIdx.x & 31, ty = threadIdx.x >> 5;
  #pragma unroll
  for (int i = 0; i < 4; ++i) {
    int k = kb + ty + i * 8, n = nb + tx;
    tile[ty + i * 8][tx] = (k < K && n < N) ? W[(size_t)k * N + n] : 0.f;
  }
  __syncthreads();
  #pragma unroll
  for (int i = 0; i < 4; ++i) {
    int n = nb + ty + i * 8, k = kb + tx;
    WT[(size_t)n * KPAD + k] = f2b(tile[tx][ty + i * 8]);
  }
}

__global__ __launch_bounds__(256) void prep_all(
    const float* __restrict__ x, u16* __restrict__ xb,
    const float* __restrict__ W1, u16* __restrict__ w1t,
    const float* __restrict__ W2, u16* __restrict__ w2t,
    const float* __restrict__ W3, u16* __restrict__ w3t,
    const float* __restrict__ Wd1, u16* __restrict__ wd1t,
    const float* __restrict__ Wd2, u16* __restrict__ wd2t,
    const float* __restrict__ bd1, float* __restrict__ bd1p,
    const float* __restrict__ bd2, float* __restrict__ bd2p,
    const int* __restrict__ dst, int* __restrict__ cnt1,
    int* __restrict__ cnt2) {
  __shared__ float tile[32][33];
  const int b = blockIdx.x;
  const int tid = threadIdx.x;
  if (b < 512) {
    wT_tile(W1, w1t, 512, 1024, 512, 1024, b % 32, b / 32, tile);
  } else if (b < 1024) {
    int t = b - 512;  wT_tile(W2, w2t, 1024, 512, 1024, 512, t % 16, t / 16, tile);
  } else if (b < 1088) {
    int t = b - 1024; wT_tile(W3, w3t, 512, 128, 512, 128, t % 4, t / 4, tile);
  } else if (b < 1120) {
    int t = b - 1088; wT_tile(Wd1, wd1t, 128, 152, 128, 256, t % 8, t / 8, tile);
  } else if (b < 1152) {
    int t = b - 1120; wT_tile(Wd2, wd2t, 152, 48, 256, 128, t % 4, t / 4, tile);
  } else if (b < 11152) {
    int idx = ((b - 1152) * 256 + tid) * 4;
    if (idx < 20000 * 512) {
      float4 v = *reinterpret_cast<const float4*>(&x[idx]);
      uint2 o;
      o.x = cvt_pk_bf16(v.x, v.y);
      o.y = cvt_pk_bf16(v.z, v.w);
      *reinterpret_cast<uint2*>(&xb[idx]) = o;
    }
  } else if (b == 11152) {
    bd1p[tid] = (tid < 152) ? bd1[tid] : 0.f;
  } else if (b == 11153) {
    if (tid < 128) bd2p[tid] = (tid < 48) ? bd2[tid] : 0.f;
  } else if (b < 12404) {
    int e = (b - 11154) * 256 + tid;
    if (e < 320000) atomicAdd(&cnt1[dst[e]], 1);
  } else {
    int i = (b - 12404) * 256 + tid;
    if (i < 20000) cnt2[i] = 0;
  }
}

// ----------------------- two-level exclusive scan --------------------------
__global__ __launch_bounds__(1024) void scan_part(
    const int* __restrict__ in, int* __restrict__ out,
    int* __restrict__ bsum, int n) {
  __shared__ int wsum[16];
  const int lane = threadIdx.x & 63, wv = threadIdx.x >> 6;
  int i = blockIdx.x * 1024 + threadIdx.x;
  int v = (i < n) ? in[i] : 0;
  int s = v;
  #pragma unroll
  for (int off = 1; off < 64; off <<= 1) {
    int t = __shfl_up(s, off, 64);
    if (lane >= off) s += t;
  }
  if (lane == 63) wsum[wv] = s;
  __syncthreads();
  if (wv == 0 && lane < 16) {
    int t = wsum[lane];
    #pragma unroll
    for (int off = 1; off < 16; off <<= 1) {
      int u = __shfl_up(t, off, 64);
      if (lane >= off) t += u;
    }
    wsum[lane] = t;
  }
  __syncthreads();
  int waveoff = (wv == 0) ? 0 : wsum[wv - 1];
  if (i < n) out[i] = waveoff + s - v;
  if (threadIdx.x == 0) bsum[blockIdx.x] = wsum[15];
}
__global__ __launch_bounds__(1024) void scan_fix(
    int* __restrict__ out, const int* __restrict__ bsum, int n, int nb) {
  int b = blockIdx.x;
  int pre = 0, tot = 0;
  for (int j = 0; j < nb; ++j) {
    int v = bsum[j];
    if (j < b) pre += v;
    tot += v;
  }
  int i = b * 1024 + threadIdx.x;
  if (i < n && b > 0) out[i] += pre;
  if (b == 0 && threadIdx.x == 0) out[n] = tot;
}

// scatter edges to CSR order, packed as (bf16(w) << 16) | u16(src)
__global__ __launch_bounds__(256) void scatter_csr(
    const int* __restrict__ dst, const int* __restrict__ src,
    const float* __restrict__ ew, const int* __restrict__ row_ptr,
    int* __restrict__ cnt, unsigned int* __restrict__ csr_pack, int E) {
  int e = blockIdx.x * 256 + threadIdx.x;
  if (e >= E) return;
  int d = dst[e];
  int pos = row_ptr[d] + atomicAdd(&cnt[d], 1);
  csr_pack[pos] = ((unsigned int)f2b(ew[e]) << 16) | (unsigned int)src[e];
}

// ----------------------- 128x128 2-phase MFMA GEMM (R8-proven) --------------
template <int ACT, bool BIAS, bool OUT_BF16>
__global__ __launch_bounds__(256) void gemm_mfma_db(
    const u16* __restrict__ A, const u16* __restrict__ BT,
    const float* __restrict__ bias, void* __restrict__ C,
    int M, int K, int Nn) {
  __shared__ __align__(16) u16 As[2][128 * 64];
  __shared__ __align__(16) u16 Bs[2][128 * 64];
  const int tid = threadIdx.x;
  const int lane = tid & 63;
  const int wave = tid >> 6;
  const int lo = lane & 15, hi = lane >> 4;
  const int wr = wave >> 1, wc = wave & 1;

  const int gx = gridDim.x;
  const int nwg = gx * gridDim.y;
  const int wg = blockIdx.y * gx + blockIdx.x;
  const int q = nwg >> 3, r = nwg & 7;
  const int xcd = wg & 7, sidx = wg >> 3;
  const int swz = (xcd < r ? xcd * (q + 1) : r * (q + 1) + (xcd - r) * q) + sidx;
  const int row0 = (swz / gx) * 128;
  const int col0 = (swz % gx) * 128;

  const u16* pa[4];
  const u16* pb[4];
  int so[4];
  #pragma unroll
  for (int i = 0; i < 4; ++i) {
    int o = i * 4096 + tid * 16;
    int rr = o >> 7;
    int ke = ((o & 127) >> 1) ^ ((rr & 7) << 3);
    pa[i] = &A[(size_t)(row0 + rr) * K + ke];
    pb[i] = &BT[(size_t)(col0 + rr) * K + ke];
    so[i] = o >> 1;
  }

  const int nk = K >> 6;
  f32x4 acc[4][4] = {};

  auto STAGE = [&](int buf, int kt) {
    const int ko = kt << 6;
    #pragma unroll
    for (int i = 0; i < 4; ++i) {
      __builtin_amdgcn_global_load_lds(
          (const AS1 void*)(pa[i] + ko),
          (AS3 void*)&As[buf][so[i]], 16, 0, 0);
      __builtin_amdgcn_global_load_lds(
          (const AS1 void*)(pb[i] + ko),
          (AS3 void*)&Bs[buf][so[i]], 16, 0, 0);
    }
  };

  STAGE(0, 0);
  STAGE(1, 1);
  asm volatile("s_waitcnt vmcnt(8)" ::: "memory");
  __builtin_amdgcn_s_barrier();

  auto body = [&](int cur, int kt) {
    bf16x8 af[2][4], bfr[2][4];
    #pragma unroll
    for (int ks = 0; ks < 2; ++ks) {
      #pragma unroll
      for (int m = 0; m < 4; ++m) {
        int row = wr * 64 + m * 16 + lo;
        int idx = (row * 64 + ks * 32 + hi * 8) ^ ((row & 7) << 3);
        af[ks][m] = *reinterpret_cast<const bf16x8*>(&As[cur][idx]);
      }
      #pragma unroll
      for (int n = 0; n < 4; ++n) {
        int col = wc * 64 + n * 16 + lo;
        int idx = (col * 64 + ks * 32 + hi * 8) ^ ((col & 7) << 3);
        bfr[ks][n] = *reinterpret_cast<const bf16x8*>(&Bs[cur][idx]);
      }
    }
    __builtin_amdgcn_s_setprio(1);
    #pragma unroll
    for (int ks = 0; ks < 2; ++ks)
      #pragma unroll
      for (int m = 0; m < 4; ++m)
        #pragma unroll
        for (int n = 0; n < 4; ++n)
          acc[m][n] = __builtin_amdgcn_mfma_f32_16x16x32_bf16(
              af[ks][m], bfr[ks][n], acc[m][n], 0, 0, 0);
    __builtin_amdgcn_s_setprio(0);
    asm volatile("s_waitcnt lgkmcnt(0)" ::: "memory");
    __builtin_amdgcn_s_barrier();
    if (kt + 2 < nk) {
      STAGE(cur, kt + 2);
      asm volatile("s_waitcnt vmcnt(8)" ::: "memory");
    } else if (kt + 1 < nk) {
      asm volatile("s_waitcnt vmcnt(0)" ::: "memory");
    }
    __builtin_amdgcn_s_barrier();
  };

  for (int kt = 0; kt < nk; kt += 2) {   // all nk are even (2,4,8,16)
    body(0, kt);
    body(1, kt + 1);
  }

  float bv[4];
  if (BIAS) {
    #pragma unroll
    for (int n = 0; n < 4; ++n) bv[n] = bias[col0 + wc * 64 + n * 16 + lo];
  }

  u16* Cb = (u16*)C;
  float* Cf = (float*)C;
  #pragma unroll
  for (int m = 0; m < 4; ++m) {
    int rbase = row0 + wr * 64 + m * 16 + hi * 4;
    #pragma unroll
    for (int n = 0; n < 4; ++n) {
      int c = col0 + wc * 64 + n * 16 + lo;
      float vv[4];
      #pragma unroll
      for (int i = 0; i < 4; ++i) {
        float v = acc[m][n][i];
        if (BIAS) v += bv[n];
        if (ACT == 1) v = fast_tanh(v);
        else if (ACT == 2) v = fmaxf(v, 0.f);
        vv[i] = v;
      }
      if (OUT_BF16) {
        unsigned int r01 = cvt_pk_bf16(vv[0], vv[1]);
        unsigned int r23 = cvt_pk_bf16(vv[2], vv[3]);
        u16* p = Cb + (size_t)rbase * Nn + c;
        p[0]              = (u16)r01;
        p[Nn]             = (u16)(r01 >> 16);
        p[2 * (size_t)Nn] = (u16)r23;
        p[3 * (size_t)Nn] = (u16)(r23 >> 16);
      } else {
        float* p = Cf + (size_t)rbase * Nn + c;
        p[0] = vv[0]; p[Nn] = vv[1];
        p[2 * (size_t)Nn] = vv[2]; p[3 * (size_t)Nn] = vv[3];
      }
    }
  }
}

// ----------------------- spmm: XCD-sharded column slices --------------------
// out[i][cslice] = act( sum_p w * H[src][cslice] (+bias) ).
// CHUNKS slices of F/CHUNKS(=64) cols; chunk = blockIdx % CHUNKS pins each
// slice to one XCD (empirical round-robin) -> per-XCD working set 2.56 MB
// fits the 4 MB private L2. 16 nodes/block, 16-lane groups, ushort4 gathers.
template <int F, int CHUNKS, int ACT, bool BIAS, bool OUT_BF16>
__global__ __launch_bounds__(256) void spmm_xcd(
    const int* __restrict__ row_ptr, const unsigned int* __restrict__ pack,
    const u16* __restrict__ H, const float* __restrict__ bias,
    void* __restrict__ out, int N) {
  const int ci = blockIdx.x % CHUNKS;
  const int nb = blockIdx.x / CHUNKS;
  const int g = threadIdx.x >> 4;          // 16 groups = 16 nodes
  const int gl = threadIdx.x & 15;
  const int node = nb * 16 + g;
  if (node >= N) return;
  const int c0 = ci * (F / CHUNKS) + gl * 4;
  const int beg = row_ptr[node], end = row_ptr[node + 1];

  float a0 = 0.f, a1 = 0.f, a2 = 0.f, a3 = 0.f;
  int p = beg;
  for (; p + 3 < end; p += 4) {
    unsigned int k0 = pack[p], k1 = pack[p + 1], k2 = pack[p + 2], k3 = pack[p + 3];
    ushort4 h0 = *reinterpret_cast<const ushort4*>(&H[(size_t)(k0 & 0xFFFFu) * F + c0]);
    ushort4 h1 = *reinterpret_cast<const ushort4*>(&H[(size_t)(k1 & 0xFFFFu) * F + c0]);
    ushort4 h2 = *reinterpret_cast<const ushort4*>(&H[(size_t)(k2 & 0xFFFFu) * F + c0]);
    ushort4 h3 = *reinterpret_cast<const ushort4*>(&H[(size_t)(k3 & 0xFFFFu) * F + c0]);
    float w0 = b2f((u16)(k0 >> 16)), w1 = b2f((u16)(k1 >> 16));
    float w2 = b2f((u16)(k2 >> 16)), w3 = b2f((u16)(k3 >> 16));
    a0 += w0 * b2f(h0.x) + w1 * b2f(h1.x) + w2 * b2f(h2.x) + w3 * b2f(h3.x);
    a1 += w0 * b2f(h0.y) + w1 * b2f(h1.y) + w2 * b2f(h2.y) + w3 * b2f(h3.y);
    a2 += w0 * b2f(h0.z) + w1 * b2f(h1.z) + w2 * b2f(h2.z) + w3 * b2f(h3.z);
    a3 += w0 * b2f(h0.w) + w1 * b2f(h1.w) + w2 * b2f(h2.w) + w3 * b2f(h3.w);
  }
  for (; p < end; ++p) {
    unsigned int k0 = pack[p];
    ushort4 h0 = *reinterpret_cast<const ushort4*>(&H[(size_t)(k0 & 0xFFFFu) * F + c0]);
    float w0 = b2f((u16)(k0 >> 16));
    a0 += w0 * b2f(h0.x); a1 += w0 * b2f(h0.y);
    a2 += w0 * b2f(h0.z); a3 += w0 * b2f(h0.w);
  }
  if (BIAS) {
    a0 += bias[c0]; a1 += bias[c0 + 1]; a2 += bias[c0 + 2]; a3 += bias[c0 + 3];
  }
  if (ACT == 1) {
    a0 = fast_tanh(a0); a1 = fast_tanh(a1);
    a2 = fast_tanh(a2); a3 = fast_tanh(a3);
  }
  if (OUT_BF16) {
    uint2 o;
    o.x = cvt_pk_bf16(a0, a1);
    o.y = cvt_pk_bf16(a2, a3);
    *reinterpret_cast<uint2*>(&((u16*)out)[(size_t)node * F + c0]) = o;
  } else {
    float4 o = make_float4(a0, a1, a2, a3);
    *reinterpret_cast<float4*>(&((float*)out)[(size_t)node * F + c0]) = o;
  }
}

// out[r] = dot(D2row(bf16)[:48], W[:48]) + b[0]
__global__ __launch_bounds__(256) void last_layer_bf16(
    const u16* __restrict__ D2v, const float* __restrict__ W,
    const float* __restrict__ b, float* __restrict__ out,
    int M, int K, int ld) {
  int rr = blockIdx.x * 256 + threadIdx.x;
  if (rr >= M) return;
  float s = b[0];
  const u16* row = &D2v[(size_t)rr * ld];
  #pragma unroll 8
  for (int k = 0; k < 48; ++k) s += b2f(row[k]) * W[k];
  out[rr] = s;
}

// ---------------------------------------------------------------------------

extern "C" void kernel_launch(void* const* d_in, const int* in_sizes, int n_in,
                              void* d_out, int out_size, void* d_ws, size_t ws_size,
                              hipStream_t stream) {
  const int N = 20000, E = 320000;
  const int F_IN = 512, H1 = 1024, H2 = 512, F_OUT = 128;
  const int D1P = 256, D2P = 128;

  const float* x    = (const float*)d_in[0];
  const int*   src  = (const int*)d_in[1];
  const int*   dst  = (const int*)d_in[2];
  const float* ew   = (const float*)d_in[3];
  const float* W1   = (const float*)d_in[4];
  const float* b1   = (const float*)d_in[5];
  const float* W2   = (const float*)d_in[6];
  const float* b2   = (const float*)d_in[7];
  const float* W3   = (const float*)d_in[8];
  const float* b3   = (const float*)d_in[9];
  const float* Wd1  = (const float*)d_in[10];
  const float* bd1  = (const float*)d_in[11];
  const float* Wd2  = (const float*)d_in[12];
  const float* bd2  = (const float*)d_in[13];
  const float* Wd3  = (const float*)d_in[14];
  const float* bd3  = (const float*)d_in[15];
  float* out = (float*)d_out;

  size_t off = 0;
  auto alloc = [&](size_t bytes) {
    void* p = (char*)d_ws + off;
    off += (bytes + 255) & ~(size_t)255;
    return p;
  };
  u16* xb   = (u16*)alloc((size_t)MPAD * F_IN * 2);    // x bf16; later t2
  u16* ax   = (u16*)alloc((size_t)MPAD * F_IN * 2);    // A@x;   later h2
  u16* h1   = (u16*)alloc((size_t)MPAD * H1 * 2);      // h1 (also t3..d2 region)
  u16* w1t  = (u16*)alloc((size_t)H1 * F_IN * 2);
  u16* w2t  = (u16*)alloc((size_t)H2 * H1 * 2);
  u16* w3t  = (u16*)alloc((size_t)F_OUT * H2 * 2);
  u16* wd1t = (u16*)alloc((size_t)D1P * F_OUT * 2);
  u16* wd2t = (u16*)alloc((size_t)D2P * D1P * 2);
  float* bd1p = (float*)alloc((size_t)D1P * 4);
  float* bd2p = (float*)alloc((size_t)D2P * 4);
  int* row_ptr = (int*)alloc((size_t)(N + 1) * 4);
  int* cnt1    = (int*)alloc((size_t)N * 4);
  int* cnt2    = (int*)alloc((size_t)N * 4);
  int* bsum    = (int*)alloc((size_t)32 * 4);
  unsigned int* csr_pack = (unsigned int*)alloc((size_t)E * 4);

  u16* t2 = xb;
  u16* h2 = ax;
  u16* t3 = h1;
  u16* gb = t3 + (size_t)MPAD * F_OUT;
  u16* d1 = gb + (size_t)MPAD * F_OUT;
  u16* d2 = d1 + (size_t)MPAD * D1P;

  auto cdiv = [](int a, int b) { return (a + b - 1) / b; };
  const int NB16 = cdiv(N, 16);   // 1250

  // ---- prep ----
  hipMemsetAsync(cnt1, 0, (size_t)N * 4, stream);
  prep_all<<<12483, 256, 0, stream>>>(x, xb, W1, w1t, W2, w2t, W3, w3t,
                                      Wd1, wd1t, Wd2, wd2t, bd1, bd1p,
                                      bd2, bd2p, dst, cnt1, cnt2);
  scan_part<<<20, 1024, 0, stream>>>(cnt1, row_ptr, bsum, N);
  scan_fix<<<20, 1024, 0, stream>>>(row_ptr, bsum, N, 20);
  scatter_csr<<<cdiv(E, 256), 256, 0, stream>>>(dst, src, ew, row_ptr, cnt2,
                                                csr_pack, E);

  // ---- layer 1 (reordered): ax = A@x ; h1 = tanh(ax@W1 + b1) ----
  spmm_xcd<512, 8, 0, false, true><<<NB16 * 8, 256, 0, stream>>>(
      row_ptr, csr_pack, xb, nullptr, ax, N);
  gemm_mfma_db<1, true, true><<<dim3(H1 / 128, MPAD / 128), 256, 0, stream>>>(
      ax, w1t, b1, h1, MPAD, F_IN, H1);

  // ---- layer 2: t2 = h1@W2 ; h2 = tanh(A@t2 + b2) ----
  gemm_mfma_db<0, false, true><<<dim3(H2 / 128, MPAD / 128), 256, 0, stream>>>(
      h1, w2t, nullptr, t2, MPAD, H1, H2);
  spmm_xcd<512, 8, 1, true, true><<<NB16 * 8, 256, 0, stream>>>(
      row_ptr, csr_pack, t2, b2, h2, N);

  // ---- layer 3: t3 = h2@W3 ; gb = A@t3 + b3 (bf16) ----
  gemm_mfma_db<0, false, true><<<dim3(F_OUT / 128, MPAD / 128), 256, 0, stream>>>(
      h2, w3t, nullptr, t3, MPAD, H2, F_OUT);
  spmm_xcd<128, 2, 0, true, true><<<NB16 * 2, 256, 0, stream>>>(
      row_ptr, csr_pack, t3, b3, gb, N);

  // ---- dense head (bf16 MFMA, padded widths) ----
  gemm_mfma_db<2, true, true><<<dim3(D1P / 128, MPAD / 128), 256, 0, stream>>>(
      gb, wd1t, bd1p, d1, MPAD, F_OUT, D1P);
  gemm_mfma_db<2, true, true><<<dim3(D2P / 128, MPAD / 128), 256, 0, stream>>>(
      d1, wd2t, bd2p, d2, MPAD, D1P, D2P);
  last_layer_bf16<<<cdiv(N, 256), 256, 0, stream>>>(d2, Wd3, bd3, out, N, 48, D2P);
}

// Round 12
// 217.668 us; speedup vs baseline: 1.3635x; 1.1267x over previous
//
#include <hip/hip_runtime.h>
#include <hip/hip_bf16.h>

// ---------------------------------------------------------------------------
// GCN (3x GCNConv) + dense head, bf16 MFMA.
// Round 12: spmm latency fix — software-pipelined pack prefetch (one L2
// round trip per 4-edge group instead of two), 8 cols/lane ushort8 gathers
// (half the gather count, amortized decode), 32 nodes/block. XCD sharding
// kept (CHUNKS=8 -> 2.56 MB/XCD slice). GEMM/prep/CSR = R11 (proven 245 us).
// ---------------------------------------------------------------------------

typedef __attribute__((ext_vector_type(8))) short bf16x8;
typedef __attribute__((ext_vector_type(4))) float f32x4;
typedef unsigned short u16;
typedef unsigned int u32;

#define MPAD 20096   // 157 * 128
#define AS1 __attribute__((address_space(1)))
#define AS3 __attribute__((address_space(3)))

__device__ inline u16 f2b(float f) {
  union { float f; u32 u; } x; x.f = f;
  u32 r = x.u + 0x7FFFu + ((x.u >> 16) & 1u);   // RNE
  return (u16)(r >> 16);
}
__device__ inline float b2f(u16 u) {
  union { u32 u; float f; } x; x.u = ((u32)u) << 16; return x.f;
}
__device__ inline float lo_f(u32 u) {          // low bf16 of a packed u32
  union { u32 u; float f; } x; x.u = u << 16; return x.f;
}
__device__ inline float hi_f(u32 u) {          // high bf16 of a packed u32
  union { u32 u; float f; } x; x.u = u & 0xFFFF0000u; return x.f;
}
__device__ inline unsigned int cvt_pk_bf16(float lo, float hi) {
  unsigned int r;
  asm("v_cvt_pk_bf16_f32 %0, %1, %2" : "=v"(r) : "v"(lo), "v"(hi));
  return r;
}
// tanh(x) = (e^2x - 1)/(e^2x + 1); clamped. ~1e-7 rel err.
__device__ inline float fast_tanh(float x) {
  float cx = fminf(fmaxf(x, -9.f), 9.f);
  float e = __expf(2.f * cx);
  float d = e + 1.f, r;
  asm("v_rcp_f32 %0, %1" : "=v"(r) : "v"(d));
  return (e - 1.f) * r;
}

// ----------------------- fused prep kernel ---------------------------------

__device__ inline void wT_tile(const float* __restrict__ W, u16* __restrict__ WT,
                               int K, int N, int KPAD, int NPAD,
                               int bx, int by, float (*tile)[33]) {
  const int kb = by * 32, nb = bx * 32;
  const int tx = threadIdx.x & 31, ty = threadIdx.x >> 5;
  #pragma unroll
  for (int i = 0; i < 4; ++i) {
    int k = kb + ty + i * 8, n = nb + tx;
    tile[ty + i * 8][tx] = (k < K && n < N) ? W[(size_t)k * N + n] : 0.f;
  }
  __syncthreads();
  #pragma unroll
  for (int i = 0; i < 4; ++i) {
    int n = nb + ty + i * 8, k = kb + tx;
    WT[(size_t)n * KPAD + k] = f2b(tile[tx][ty + i * 8]);
  }
}

__global__ __launch_bounds__(256) void prep_all(
    const float* __restrict__ x, u16* __restrict__ xb,
    const float* __restrict__ W1, u16* __restrict__ w1t,
    const float* __restrict__ W2, u16* __restrict__ w2t,
    const float* __restrict__ W3, u16* __restrict__ w3t,
    const float* __restrict__ Wd1, u16* __restrict__ wd1t,
    const float* __restrict__ Wd2, u16* __restrict__ wd2t,
    const float* __restrict__ bd1, float* __restrict__ bd1p,
    const float* __restrict__ bd2, float* __restrict__ bd2p,
    const int* __restrict__ dst, int* __restrict__ cnt1,
    int* __restrict__ cnt2) {
  __shared__ float tile[32][33];
  const int b = blockIdx.x;
  const int tid = threadIdx.x;
  if (b < 512) {
    wT_tile(W1, w1t, 512, 1024, 512, 1024, b % 32, b / 32, tile);
  } else if (b < 1024) {
    int t = b - 512;  wT_tile(W2, w2t, 1024, 512, 1024, 512, t % 16, t / 16, tile);
  } else if (b < 1088) {
    int t = b - 1024; wT_tile(W3, w3t, 512, 128, 512, 128, t % 4, t / 4, tile);
  } else if (b < 1120) {
    int t = b - 1088; wT_tile(Wd1, wd1t, 128, 152, 128, 256, t % 8, t / 8, tile);
  } else if (b < 1152) {
    int t = b - 1120; wT_tile(Wd2, wd2t, 152, 48, 256, 128, t % 4, t / 4, tile);
  } else if (b < 11152) {
    int idx = ((b - 1152) * 256 + tid) * 4;
    if (idx < 20000 * 512) {
      float4 v = *reinterpret_cast<const float4*>(&x[idx]);
      uint2 o;
      o.x = cvt_pk_bf16(v.x, v.y);
      o.y = cvt_pk_bf16(v.z, v.w);
      *reinterpret_cast<uint2*>(&xb[idx]) = o;
    }
  } else if (b == 11152) {
    bd1p[tid] = (tid < 152) ? bd1[tid] : 0.f;
  } else if (b == 11153) {
    if (tid < 128) bd2p[tid] = (tid < 48) ? bd2[tid] : 0.f;
  } else if (b < 12404) {
    int e = (b - 11154) * 256 + tid;
    if (e < 320000) atomicAdd(&cnt1[dst[e]], 1);
  } else {
    int i = (b - 12404) * 256 + tid;
    if (i < 20000) cnt2[i] = 0;
  }
}

// ----------------------- two-level exclusive scan --------------------------
__global__ __launch_bounds__(1024) void scan_part(
    const int* __restrict__ in, int* __restrict__ out,
    int* __restrict__ bsum, int n) {
  __shared__ int wsum[16];
  const int lane = threadIdx.x & 63, wv = threadIdx.x >> 6;
  int i = blockIdx.x * 1024 + threadIdx.x;
  int v = (i < n) ? in[i] : 0;
  int s = v;
  #pragma unroll
  for (int off = 1; off < 64; off <<= 1) {
    int t = __shfl_up(s, off, 64);
    if (lane >= off) s += t;
  }
  if (lane == 63) wsum[wv] = s;
  __syncthreads();
  if (wv == 0 && lane < 16) {
    int t = wsum[lane];
    #pragma unroll
    for (int off = 1; off < 16; off <<= 1) {
      int u = __shfl_up(t, off, 64);
      if (lane >= off) t += u;
    }
    wsum[lane] = t;
  }
  __syncthreads();
  int waveoff = (wv == 0) ? 0 : wsum[wv - 1];
  if (i < n) out[i] = waveoff + s - v;
  if (threadIdx.x == 0) bsum[blockIdx.x] = wsum[15];
}
__global__ __launch_bounds__(1024) void scan_fix(
    int* __restrict__ out, const int* __restrict__ bsum, int n, int nb) {
  int b = blockIdx.x;
  int pre = 0, tot = 0;
  for (int j = 0; j < nb; ++j) {
    int v = bsum[j];
    if (j < b) pre += v;
    tot += v;
  }
  int i = b * 1024 + threadIdx.x;
  if (i < n && b > 0) out[i] += pre;
  if (b == 0 && threadIdx.x == 0) out[n] = tot;
}

// scatter edges to CSR order, packed as (bf16(w) << 16) | u16(src)
__global__ __launch_bounds__(256) void scatter_csr(
    const int* __restrict__ dst, const int* __restrict__ src,
    const float* __restrict__ ew, const int* __restrict__ row_ptr,
    int* __restrict__ cnt, u32* __restrict__ csr_pack, int E) {
  int e = blockIdx.x * 256 + threadIdx.x;
  if (e >= E) return;
  int d = dst[e];
  int pos = row_ptr[d] + atomicAdd(&cnt[d], 1);
  csr_pack[pos] = ((u32)f2b(ew[e]) << 16) | (u32)src[e];
}

// ----------------------- 128x128 2-phase MFMA GEMM (R8-proven) --------------
template <int ACT, bool BIAS, bool OUT_BF16>
__global__ __launch_bounds__(256) void gemm_mfma_db(
    const u16* __restrict__ A, const u16* __restrict__ BT,
    const float* __restrict__ bias, void* __restrict__ C,
    int M, int K, int Nn) {
  __shared__ __align__(16) u16 As[2][128 * 64];
  __shared__ __align__(16) u16 Bs[2][128 * 64];
  const int tid = threadIdx.x;
  const int lane = tid & 63;
  const int wave = tid >> 6;
  const int lo = lane & 15, hi = lane >> 4;
  const int wr = wave >> 1, wc = wave & 1;

  const int gx = gridDim.x;
  const int nwg = gx * gridDim.y;
  const int wg = blockIdx.y * gx + blockIdx.x;
  const int q = nwg >> 3, r = nwg & 7;
  const int xcd = wg & 7, sidx = wg >> 3;
  const int swz = (xcd < r ? xcd * (q + 1) : r * (q + 1) + (xcd - r) * q) + sidx;
  const int row0 = (swz / gx) * 128;
  const int col0 = (swz % gx) * 128;

  const u16* pa[4];
  const u16* pb[4];
  int so[4];
  #pragma unroll
  for (int i = 0; i < 4; ++i) {
    int o = i * 4096 + tid * 16;
    int rr = o >> 7;
    int ke = ((o & 127) >> 1) ^ ((rr & 7) << 3);
    pa[i] = &A[(size_t)(row0 + rr) * K + ke];
    pb[i] = &BT[(size_t)(col0 + rr) * K + ke];
    so[i] = o >> 1;
  }

  const int nk = K >> 6;
  f32x4 acc[4][4] = {};

  auto STAGE = [&](int buf, int kt) {
    const int ko = kt << 6;
    #pragma unroll
    for (int i = 0; i < 4; ++i) {
      __builtin_amdgcn_global_load_lds(
          (const AS1 void*)(pa[i] + ko),
          (AS3 void*)&As[buf][so[i]], 16, 0, 0);
      __builtin_amdgcn_global_load_lds(
          (const AS1 void*)(pb[i] + ko),
          (AS3 void*)&Bs[buf][so[i]], 16, 0, 0);
    }
  };

  STAGE(0, 0);
  STAGE(1, 1);
  asm volatile("s_waitcnt vmcnt(8)" ::: "memory");
  __builtin_amdgcn_s_barrier();

  auto body = [&](int cur, int kt) {
    bf16x8 af[2][4], bfr[2][4];
    #pragma unroll
    for (int ks = 0; ks < 2; ++ks) {
      #pragma unroll
      for (int m = 0; m < 4; ++m) {
        int row = wr * 64 + m * 16 + lo;
        int idx = (row * 64 + ks * 32 + hi * 8) ^ ((row & 7) << 3);
        af[ks][m] = *reinterpret_cast<const bf16x8*>(&As[cur][idx]);
      }
      #pragma unroll
      for (int n = 0; n < 4; ++n) {
        int col = wc * 64 + n * 16 + lo;
        int idx = (col * 64 + ks * 32 + hi * 8) ^ ((col & 7) << 3);
        bfr[ks][n] = *reinterpret_cast<const bf16x8*>(&Bs[cur][idx]);
      }
    }
    __builtin_amdgcn_s_setprio(1);
    #pragma unroll
    for (int ks = 0; ks < 2; ++ks)
      #pragma unroll
      for (int m = 0; m < 4; ++m)
        #pragma unroll
        for (int n = 0; n < 4; ++n)
          acc[m][n] = __builtin_amdgcn_mfma_f32_16x16x32_bf16(
              af[ks][m], bfr[ks][n], acc[m][n], 0, 0, 0);
    __builtin_amdgcn_s_setprio(0);
    asm volatile("s_waitcnt lgkmcnt(0)" ::: "memory");
    __builtin_amdgcn_s_barrier();
    if (kt + 2 < nk) {
      STAGE(cur, kt + 2);
      asm volatile("s_waitcnt vmcnt(8)" ::: "memory");
    } else if (kt + 1 < nk) {
      asm volatile("s_waitcnt vmcnt(0)" ::: "memory");
    }
    __builtin_amdgcn_s_barrier();
  };

  for (int kt = 0; kt < nk; kt += 2) {   // all nk are even (2,4,8,16)
    body(0, kt);
    body(1, kt + 1);
  }

  float bv[4];
  if (BIAS) {
    #pragma unroll
    for (int n = 0; n < 4; ++n) bv[n] = bias[col0 + wc * 64 + n * 16 + lo];
  }

  u16* Cb = (u16*)C;
  float* Cf = (float*)C;
  #pragma unroll
  for (int m = 0; m < 4; ++m) {
    int rbase = row0 + wr * 64 + m * 16 + hi * 4;
    #pragma unroll
    for (int n = 0; n < 4; ++n) {
      int c = col0 + wc * 64 + n * 16 + lo;
      float vv[4];
      #pragma unroll
      for (int i = 0; i < 4; ++i) {
        float v = acc[m][n][i];
        if (BIAS) v += bv[n];
        if (ACT == 1) v = fast_tanh(v);
        else if (ACT == 2) v = fmaxf(v, 0.f);
        vv[i] = v;
      }
      if (OUT_BF16) {
        unsigned int r01 = cvt_pk_bf16(vv[0], vv[1]);
        unsigned int r23 = cvt_pk_bf16(vv[2], vv[3]);
        u16* p = Cb + (size_t)rbase * Nn + c;
        p[0]              = (u16)r01;
        p[Nn]             = (u16)(r01 >> 16);
        p[2 * (size_t)Nn] = (u16)r23;
        p[3 * (size_t)Nn] = (u16)(r23 >> 16);
      } else {
        float* p = Cf + (size_t)rbase * Nn + c;
        p[0] = vv[0]; p[Nn] = vv[1];
        p[2 * (size_t)Nn] = vv[2]; p[3 * (size_t)Nn] = vv[3];
      }
    }
  }
}

// ----------------------- spmm: pipelined, XCD-sharded -----------------------
// out[i][slice] = act( sum_p w * H[src][slice] (+bias) ).  H bf16.
// 8 lanes/node x 8 cols (ushort8 16B gathers), 32 nodes/block.
// chunk = blockIdx % CHUNKS pins a 64-col slice per XCD (2.56 MB < 4 MB L2).
// Pack records for the NEXT 4-edge group are prefetched during the current
// group's gathers -> one L2 round trip per group instead of two.
template <int F, int CHUNKS, int ACT, bool BIAS, bool OUT_BF16>
__global__ __launch_bounds__(256) void spmm_pl(
    const int* __restrict__ row_ptr, const u32* __restrict__ pack,
    const u16* __restrict__ H, const float* __restrict__ bias,
    void* __restrict__ out, int N) {
  const int ci = blockIdx.x % CHUNKS;
  const int nb = blockIdx.x / CHUNKS;
  const int g = threadIdx.x >> 3;          // 32 nodes/block
  const int gl = threadIdx.x & 7;
  const int node = nb * 32 + g;
  if (node >= N) return;
  const int c0 = ci * (F / CHUNKS) + gl * 8;
  const int beg = row_ptr[node], end = row_ptr[node + 1];

  float a[8] = {};
  int p = beg;
  u32 k0 = 0, k1 = 0, k2 = 0, k3 = 0;
  bool have = (p + 4 <= end);
  if (have) { k0 = pack[p]; k1 = pack[p + 1]; k2 = pack[p + 2]; k3 = pack[p + 3]; }
  while (have) {
    int pn = p + 4;
    bool haven = (pn + 4 <= end);
    u32 n0 = 0, n1 = 0, n2 = 0, n3 = 0;
    if (haven) { n0 = pack[pn]; n1 = pack[pn + 1]; n2 = pack[pn + 2]; n3 = pack[pn + 3]; }
    // 4 independent 16B gathers (prefetched packs already resident)
    uint4 h0 = *reinterpret_cast<const uint4*>(&H[(size_t)(k0 & 0xFFFFu) * F + c0]);
    uint4 h1 = *reinterpret_cast<const uint4*>(&H[(size_t)(k1 & 0xFFFFu) * F + c0]);
    uint4 h2 = *reinterpret_cast<const uint4*>(&H[(size_t)(k2 & 0xFFFFu) * F + c0]);
    uint4 h3 = *reinterpret_cast<const uint4*>(&H[(size_t)(k3 & 0xFFFFu) * F + c0]);
    float w0 = hi_f(k0), w1 = hi_f(k1), w2 = hi_f(k2), w3 = hi_f(k3);
    a[0] += w0 * lo_f(h0.x) + w1 * lo_f(h1.x) + w2 * lo_f(h2.x) + w3 * lo_f(h3.x);
    a[1] += w0 * hi_f(h0.x) + w1 * hi_f(h1.x) + w2 * hi_f(h2.x) + w3 * hi_f(h3.x);
    a[2] += w0 * lo_f(h0.y) + w1 * lo_f(h1.y) + w2 * lo_f(h2.y) + w3 * lo_f(h3.y);
    a[3] += w0 * hi_f(h0.y) + w1 * hi_f(h1.y) + w2 * hi_f(h2.y) + w3 * hi_f(h3.y);
    a[4] += w0 * lo_f(h0.z) + w1 * lo_f(h1.z) + w2 * lo_f(h2.z) + w3 * lo_f(h3.z);
    a[5] += w0 * hi_f(h0.z) + w1 * hi_f(h1.z) + w2 * hi_f(h2.z) + w3 * hi_f(h3.z);
    a[6] += w0 * lo_f(h0.w) + w1 * lo_f(h1.w) + w2 * lo_f(h2.w) + w3 * lo_f(h3.w);
    a[7] += w0 * hi_f(h0.w) + w1 * hi_f(h1.w) + w2 * hi_f(h2.w) + w3 * hi_f(h3.w);
    p = pn; k0 = n0; k1 = n1; k2 = n2; k3 = n3; have = haven;
  }
  for (; p < end; ++p) {                    // tail (<4 edges)
    u32 k = pack[p];
    uint4 hv = *reinterpret_cast<const uint4*>(&H[(size_t)(k & 0xFFFFu) * F + c0]);
    float wt = hi_f(k);
    a[0] += wt * lo_f(hv.x); a[1] += wt * hi_f(hv.x);
    a[2] += wt * lo_f(hv.y); a[3] += wt * hi_f(hv.y);
    a[4] += wt * lo_f(hv.z); a[5] += wt * hi_f(hv.z);
    a[6] += wt * lo_f(hv.w); a[7] += wt * hi_f(hv.w);
  }
  if (BIAS) {
    #pragma unroll
    for (int k = 0; k < 8; ++k) a[k] += bias[c0 + k];
  }
  if (ACT == 1) {
    #pragma unroll
    for (int k = 0; k < 8; ++k) a[k] = fast_tanh(a[k]);
  }
  if (OUT_BF16) {
    uint4 o;
    o.x = cvt_pk_bf16(a[0], a[1]);
    o.y = cvt_pk_bf16(a[2], a[3]);
    o.z = cvt_pk_bf16(a[4], a[5]);
    o.w = cvt_pk_bf16(a[6], a[7]);
    *reinterpret_cast<uint4*>(&((u16*)out)[(size_t)node * F + c0]) = o;
  } else {
    float* op = &((float*)out)[(size_t)node * F + c0];
    #pragma unroll
    for (int k = 0; k < 8; ++k) op[k] = a[k];
  }
}

// out[r] = dot(D2row(bf16)[:48], W[:48]) + b[0]
__global__ __launch_bounds__(256) void last_layer_bf16(
    const u16* __restrict__ D2v, const float* __restrict__ W,
    const float* __restrict__ b, float* __restrict__ out,
    int M, int K, int ld) {
  int rr = blockIdx.x * 256 + threadIdx.x;
  if (rr >= M) return;
  float s = b[0];
  const u16* row = &D2v[(size_t)rr * ld];
  #pragma unroll 8
  for (int k = 0; k < 48; ++k) s += b2f(row[k]) * W[k];
  out[rr] = s;
}

// ---------------------------------------------------------------------------

extern "C" void kernel_launch(void* const* d_in, const int* in_sizes, int n_in,
                              void* d_out, int out_size, void* d_ws, size_t ws_size,
                              hipStream_t stream) {
  const int N = 20000, E = 320000;
  const int F_IN = 512, H1 = 1024, H2 = 512, F_OUT = 128;
  const int D1P = 256, D2P = 128;

  const float* x    = (const float*)d_in[0];
  const int*   src  = (const int*)d_in[1];
  const int*   dst  = (const int*)d_in[2];
  const float* ew   = (const float*)d_in[3];
  const float* W1   = (const float*)d_in[4];
  const float* b1   = (const float*)d_in[5];
  const float* W2   = (const float*)d_in[6];
  const float* b2   = (const float*)d_in[7];
  const float* W3   = (const float*)d_in[8];
  const float* b3   = (const float*)d_in[9];
  const float* Wd1  = (const float*)d_in[10];
  const float* bd1  = (const float*)d_in[11];
  const float* Wd2  = (const float*)d_in[12];
  const float* bd2  = (const float*)d_in[13];
  const float* Wd3  = (const float*)d_in[14];
  const float* bd3  = (const float*)d_in[15];
  float* out = (float*)d_out;

  size_t off = 0;
  auto alloc = [&](size_t bytes) {
    void* p = (char*)d_ws + off;
    off += (bytes + 255) & ~(size_t)255;
    return p;
  };
  u16* xb   = (u16*)alloc((size_t)MPAD * F_IN * 2);    // x bf16; later t2
  u16* ax   = (u16*)alloc((size_t)MPAD * F_IN * 2);    // A@x;   later h2
  u16* h1   = (u16*)alloc((size_t)MPAD * H1 * 2);      // h1 (also t3..d2 region)
  u16* w1t  = (u16*)alloc((size_t)H1 * F_IN * 2);
  u16* w2t  = (u16*)alloc((size_t)H2 * H1 * 2);
  u16* w3t  = (u16*)alloc((size_t)F_OUT * H2 * 2);
  u16* wd1t = (u16*)alloc((size_t)D1P * F_OUT * 2);
  u16* wd2t = (u16*)alloc((size_t)D2P * D1P * 2);
  float* bd1p = (float*)alloc((size_t)D1P * 4);
  float* bd2p = (float*)alloc((size_t)D2P * 4);
  int* row_ptr = (int*)alloc((size_t)(N + 1) * 4);
  int* cnt1    = (int*)alloc((size_t)N * 4);
  int* cnt2    = (int*)alloc((size_t)N * 4);
  int* bsum    = (int*)alloc((size_t)32 * 4);
  u32* csr_pack = (u32*)alloc((size_t)E * 4);

  u16* t2 = xb;
  u16* h2 = ax;
  u16* t3 = h1;
  u16* gb = t3 + (size_t)MPAD * F_OUT;
  u16* d1 = gb + (size_t)MPAD * F_OUT;
  u16* d2 = d1 + (size_t)MPAD * D1P;

  auto cdiv = [](int a, int b) { return (a + b - 1) / b; };
  const int NB32 = cdiv(N, 32);   // 625

  // ---- prep ----
  hipMemsetAsync(cnt1, 0, (size_t)N * 4, stream);
  prep_all<<<12483, 256, 0, stream>>>(x, xb, W1, w1t, W2, w2t, W3, w3t,
                                      Wd1, wd1t, Wd2, wd2t, bd1, bd1p,
                                      bd2, bd2p, dst, cnt1, cnt2);
  scan_part<<<20, 1024, 0, stream>>>(cnt1, row_ptr, bsum, N);
  scan_fix<<<20, 1024, 0, stream>>>(row_ptr, bsum, N, 20);
  scatter_csr<<<cdiv(E, 256), 256, 0, stream>>>(dst, src, ew, row_ptr, cnt2,
                                                csr_pack, E);

  // ---- layer 1 (reordered): ax = A@x ; h1 = tanh(ax@W1 + b1) ----
  spmm_pl<512, 8, 0, false, true><<<NB32 * 8, 256, 0, stream>>>(
      row_ptr, csr_pack, xb, nullptr, ax, N);
  gemm_mfma_db<1, true, true><<<dim3(H1 / 128, MPAD / 128), 256, 0, stream>>>(
      ax, w1t, b1, h1, MPAD, F_IN, H1);

  // ---- layer 2: t2 = h1@W2 ; h2 = tanh(A@t2 + b2) ----
  gemm_mfma_db<0, false, true><<<dim3(H2 / 128, MPAD / 128), 256, 0, stream>>>(
      h1, w2t, nullptr, t2, MPAD, H1, H2);
  spmm_pl<512, 8, 1, true, true><<<NB32 * 8, 256, 0, stream>>>(
      row_ptr, csr_pack, t2, b2, h2, N);

  // ---- layer 3: t3 = h2@W3 ; gb = A@t3 + b3 (bf16) ----
  gemm_mfma_db<0, false, true><<<dim3(F_OUT / 128, MPAD / 128), 256, 0, stream>>>(
      h2, w3t, nullptr, t3, MPAD, H2, F_OUT);
  spmm_pl<128, 2, 0, true, true><<<NB32 * 2, 256, 0, stream>>>(
      row_ptr, csr_pack, t3, b3, gb, N);

  // ---- dense head (bf16 MFMA, padded widths) ----
  gemm_mfma_db<2, true, true><<<dim3(D1P / 128, MPAD / 128), 256, 0, stream>>>(
      gb, wd1t, bd1p, d1, MPAD, F_OUT, D1P);
  gemm_mfma_db<2, true, true><<<dim3(D2P / 128, MPAD / 128), 256, 0, stream>>>(
      d1, wd2t, bd2p, d2, MPAD, D1P, D2P);
  last_layer_bf16<<<cdiv(N, 256), 256, 0, stream>>>(d2, Wd3, bd3, out, N, 48, D2P);
}

// Round 13
// 215.798 us; speedup vs baseline: 1.3753x; 1.0087x over previous
//
#include <hip/hip_runtime.h>
#include <hip/hip_bf16.h>

// ---------------------------------------------------------------------------
// GCN (3x GCNConv) + dense head, bf16 MFMA.
// Round 13: (1) hipMemsetAsync -> zero_cnt compute kernel (removes the
// SDMA/blit graph node that cost ~40 us/replay in engine switches);
// (2) last_layer fused into head-2 GEMM epilogue (shfl-butterfly + LDS
// cross-wave reduce, writes d_out directly). Rest = R12 (proven 218 us).
// ---------------------------------------------------------------------------

typedef __attribute__((ext_vector_type(8))) short bf16x8;
typedef __attribute__((ext_vector_type(4))) float f32x4;
typedef unsigned short u16;
typedef unsigned int u32;

#define MPAD 20096   // 157 * 128
#define AS1 __attribute__((address_space(1)))
#define AS3 __attribute__((address_space(3)))

__device__ inline u16 f2b(float f) {
  union { float f; u32 u; } x; x.f = f;
  u32 r = x.u + 0x7FFFu + ((x.u >> 16) & 1u);   // RNE
  return (u16)(r >> 16);
}
__device__ inline float b2f(u16 u) {
  union { u32 u; float f; } x; x.u = ((u32)u) << 16; return x.f;
}
__device__ inline float lo_f(u32 u) {
  union { u32 u; float f; } x; x.u = u << 16; return x.f;
}
__device__ inline float hi_f(u32 u) {
  union { u32 u; float f; } x; x.u = u & 0xFFFF0000u; return x.f;
}
__device__ inline unsigned int cvt_pk_bf16(float lo, float hi) {
  unsigned int r;
  asm("v_cvt_pk_bf16_f32 %0, %1, %2" : "=v"(r) : "v"(lo), "v"(hi));
  return r;
}
// tanh(x) = (e^2x - 1)/(e^2x + 1); clamped. ~1e-7 rel err.
__device__ inline float fast_tanh(float x) {
  float cx = fminf(fmaxf(x, -9.f), 9.f);
  float e = __expf(2.f * cx);
  float d = e + 1.f, r;
  asm("v_rcp_f32 %0, %1" : "=v"(r) : "v"(d));
  return (e - 1.f) * r;
}

// ----------------------- fused prep kernel ---------------------------------

__device__ inline void wT_tile(const float* __restrict__ W, u16* __restrict__ WT,
                               int K, int N, int KPAD, int NPAD,
                               int bx, int by, float (*tile)[33]) {
  const int kb = by * 32, nb = bx * 32;
  const int tx = threadIdx.x & 31, ty = threadIdx.x >> 5;
  #pragma unroll
  for (int i = 0; i < 4; ++i) {
    int k = kb + ty + i * 8, n = nb + tx;
    tile[ty + i * 8][tx] = (k < K && n < N) ? W[(size_t)k * N + n] : 0.f;
  }
  __syncthreads();
  #pragma unroll
  for (int i = 0; i < 4; ++i) {
    int n = nb + ty + i * 8, k = kb + tx;
    WT[(size_t)n * KPAD + k] = f2b(tile[tx][ty + i * 8]);
  }
}

__global__ __launch_bounds__(256) void prep_all(
    const float* __restrict__ x, u16* __restrict__ xb,
    const float* __restrict__ W1, u16* __restrict__ w1t,
    const float* __restrict__ W2, u16* __restrict__ w2t,
    const float* __restrict__ W3, u16* __restrict__ w3t,
    const float* __restrict__ Wd1, u16* __restrict__ wd1t,
    const float* __restrict__ Wd2, u16* __restrict__ wd2t,
    const float* __restrict__ bd1, float* __restrict__ bd1p,
    const float* __restrict__ bd2, float* __restrict__ bd2p,
    const int* __restrict__ dst, int* __restrict__ cnt1,
    int* __restrict__ cnt2) {
  __shared__ float tile[32][33];
  const int b = blockIdx.x;
  const int tid = threadIdx.x;
  if (b < 512) {
    wT_tile(W1, w1t, 512, 1024, 512, 1024, b % 32, b / 32, tile);
  } else if (b < 1024) {
    int t = b - 512;  wT_tile(W2, w2t, 1024, 512, 1024, 512, t % 16, t / 16, tile);
  } else if (b < 1088) {
    int t = b - 1024; wT_tile(W3, w3t, 512, 128, 512, 128, t % 4, t / 4, tile);
  } else if (b < 1120) {
    int t = b - 1088; wT_tile(Wd1, wd1t, 128, 152, 128, 256, t % 8, t / 8, tile);
  } else if (b < 1152) {
    int t = b - 1120; wT_tile(Wd2, wd2t, 152, 48, 256, 128, t % 4, t / 4, tile);
  } else if (b < 11152) {
    int idx = ((b - 1152) * 256 + tid) * 4;
    if (idx < 20000 * 512) {
      float4 v = *reinterpret_cast<const float4*>(&x[idx]);
      uint2 o;
      o.x = cvt_pk_bf16(v.x, v.y);
      o.y = cvt_pk_bf16(v.z, v.w);
      *reinterpret_cast<uint2*>(&xb[idx]) = o;
    }
  } else if (b == 11152) {
    bd1p[tid] = (tid < 152) ? bd1[tid] : 0.f;
  } else if (b == 11153) {
    if (tid < 128) bd2p[tid] = (tid < 48) ? bd2[tid] : 0.f;
  } else if (b < 12404) {
    int e = (b - 11154) * 256 + tid;
    if (e < 320000) atomicAdd(&cnt1[dst[e]], 1);
  } else {
    int i = (b - 12404) * 256 + tid;
    if (i < 20000) cnt2[i] = 0;
  }
}

// zero cnt1 as a COMPUTE kernel (graph memset nodes go to the SDMA engine;
// the compute<->SDMA switch cost ~40 us/replay — R12 counters)
__global__ __launch_bounds__(256) void zero_cnt(int* __restrict__ c, int n) {
  int i = blockIdx.x * 256 + threadIdx.x;
  if (i < n) c[i] = 0;
}

// ----------------------- two-level exclusive scan --------------------------
__global__ __launch_bounds__(1024) void scan_part(
    const int* __restrict__ in, int* __restrict__ out,
    int* __restrict__ bsum, int n) {
  __shared__ int wsum[16];
  const int lane = threadIdx.x & 63, wv = threadIdx.x >> 6;
  int i = blockIdx.x * 1024 + threadIdx.x;
  int v = (i < n) ? in[i] : 0;
  int s = v;
  #pragma unroll
  for (int off = 1; off < 64; off <<= 1) {
    int t = __shfl_up(s, off, 64);
    if (lane >= off) s += t;
  }
  if (lane == 63) wsum[wv] = s;
  __syncthreads();
  if (wv == 0 && lane < 16) {
    int t = wsum[lane];
    #pragma unroll
    for (int off = 1; off < 16; off <<= 1) {
      int u = __shfl_up(t, off, 64);
      if (lane >= off) t += u;
    }
    wsum[lane] = t;
  }
  __syncthreads();
  int waveoff = (wv == 0) ? 0 : wsum[wv - 1];
  if (i < n) out[i] = waveoff + s - v;
  if (threadIdx.x == 0) bsum[blockIdx.x] = wsum[15];
}
__global__ __launch_bounds__(1024) void scan_fix(
    int* __restrict__ out, const int* __restrict__ bsum, int n, int nb) {
  int b = blockIdx.x;
  int pre = 0, tot = 0;
  for (int j = 0; j < nb; ++j) {
    int v = bsum[j];
    if (j < b) pre += v;
    tot += v;
  }
  int i = b * 1024 + threadIdx.x;
  if (i < n && b > 0) out[i] += pre;
  if (b == 0 && threadIdx.x == 0) out[n] = tot;
}

// scatter edges to CSR order, packed as (bf16(w) << 16) | u16(src)
__global__ __launch_bounds__(256) void scatter_csr(
    const int* __restrict__ dst, const int* __restrict__ src,
    const float* __restrict__ ew, const int* __restrict__ row_ptr,
    int* __restrict__ cnt, u32* __restrict__ csr_pack, int E) {
  int e = blockIdx.x * 256 + threadIdx.x;
  if (e >= E) return;
  int d = dst[e];
  int pos = row_ptr[d] + atomicAdd(&cnt[d], 1);
  csr_pack[pos] = ((u32)f2b(ew[e]) << 16) | (u32)src[e];
}

// ----------------------- 128x128 2-phase MFMA GEMM --------------------------
// OMODE: 0 = f32 C, 1 = bf16 C, 2 = fused d_out = relu(C)@wd3 + bd3
// (OMODE 2 requires gridDim.x == 1, i.e. Nn == 128, all cols in-block.)
template <int ACT, bool BIAS, int OMODE>
__global__ __launch_bounds__(256) void gemm_mfma_db(
    const u16* __restrict__ A, const u16* __restrict__ BT,
    const float* __restrict__ bias, void* __restrict__ C,
    int M, int K, int Nn,
    const float* __restrict__ wd3, const float* __restrict__ bd3,
    float* __restrict__ fout, int NR) {
  __shared__ __align__(16) u16 As[2][128 * 64];
  __shared__ __align__(16) u16 Bs[2][128 * 64];
  __shared__ float rs[2][128];
  const int tid = threadIdx.x;
  const int lane = tid & 63;
  const int wave = tid >> 6;
  const int lo = lane & 15, hi = lane >> 4;
  const int wr = wave >> 1, wc = wave & 1;

  const int gx = gridDim.x;
  const int nwg = gx * gridDim.y;
  const int wg = blockIdx.y * gx + blockIdx.x;
  const int q = nwg >> 3, r = nwg & 7;
  const int xcd = wg & 7, sidx = wg >> 3;
  const int swz = (xcd < r ? xcd * (q + 1) : r * (q + 1) + (xcd - r) * q) + sidx;
  const int row0 = (swz / gx) * 128;
  const int col0 = (swz % gx) * 128;

  const u16* pa[4];
  const u16* pb[4];
  int so[4];
  #pragma unroll
  for (int i = 0; i < 4; ++i) {
    int o = i * 4096 + tid * 16;
    int rr = o >> 7;
    int ke = ((o & 127) >> 1) ^ ((rr & 7) << 3);
    pa[i] = &A[(size_t)(row0 + rr) * K + ke];
    pb[i] = &BT[(size_t)(col0 + rr) * K + ke];
    so[i] = o >> 1;
  }

  const int nk = K >> 6;
  f32x4 acc[4][4] = {};

  auto STAGE = [&](int buf, int kt) {
    const int ko = kt << 6;
    #pragma unroll
    for (int i = 0; i < 4; ++i) {
      __builtin_amdgcn_global_load_lds(
          (const AS1 void*)(pa[i] + ko),
          (AS3 void*)&As[buf][so[i]], 16, 0, 0);
      __builtin_amdgcn_global_load_lds(
          (const AS1 void*)(pb[i] + ko),
          (AS3 void*)&Bs[buf][so[i]], 16, 0, 0);
    }
  };

  STAGE(0, 0);
  STAGE(1, 1);
  asm volatile("s_waitcnt vmcnt(8)" ::: "memory");
  __builtin_amdgcn_s_barrier();

  auto body = [&](int cur, int kt) {
    bf16x8 af[2][4], bfr[2][4];
    #pragma unroll
    for (int ks = 0; ks < 2; ++ks) {
      #pragma unroll
      for (int m = 0; m < 4; ++m) {
        int row = wr * 64 + m * 16 + lo;
        int idx = (row * 64 + ks * 32 + hi * 8) ^ ((row & 7) << 3);
        af[ks][m] = *reinterpret_cast<const bf16x8*>(&As[cur][idx]);
      }
      #pragma unroll
      for (int n = 0; n < 4; ++n) {
        int col = wc * 64 + n * 16 + lo;
        int idx = (col * 64 + ks * 32 + hi * 8) ^ ((col & 7) << 3);
        bfr[ks][n] = *reinterpret_cast<const bf16x8*>(&Bs[cur][idx]);
      }
    }
    __builtin_amdgcn_s_setprio(1);
    #pragma unroll
    for (int ks = 0; ks < 2; ++ks)
      #pragma unroll
      for (int m = 0; m < 4; ++m)
        #pragma unroll
        for (int n = 0; n < 4; ++n)
          acc[m][n] = __builtin_amdgcn_mfma_f32_16x16x32_bf16(
              af[ks][m], bfr[ks][n], acc[m][n], 0, 0, 0);
    __builtin_amdgcn_s_setprio(0);
    asm volatile("s_waitcnt lgkmcnt(0)" ::: "memory");
    __builtin_amdgcn_s_barrier();
    if (kt + 2 < nk) {
      STAGE(cur, kt + 2);
      asm volatile("s_waitcnt vmcnt(8)" ::: "memory");
    } else if (kt + 1 < nk) {
      asm volatile("s_waitcnt vmcnt(0)" ::: "memory");
    }
    __builtin_amdgcn_s_barrier();
  };

  for (int kt = 0; kt < nk; kt += 2) {   // all nk are even (2,4,8,16)
    body(0, kt);
    body(1, kt + 1);
  }

  float bv[4];
  if (BIAS) {
    #pragma unroll
    for (int n = 0; n < 4; ++n) bv[n] = bias[col0 + wc * 64 + n * 16 + lo];
  }
  float w3v[4];
  if (OMODE == 2) {
    #pragma unroll
    for (int n = 0; n < 4; ++n) {
      int c = wc * 64 + n * 16 + lo;
      w3v[n] = (c < 48) ? wd3[c] : 0.f;
    }
  }

  u16* Cb = (u16*)C;
  float* Cf = (float*)C;
  float pp[4][4] = {};   // [m][i] partial row-dots for OMODE 2
  #pragma unroll
  for (int m = 0; m < 4; ++m) {
    int rbase = row0 + wr * 64 + m * 16 + hi * 4;
    #pragma unroll
    for (int n = 0; n < 4; ++n) {
      int c = col0 + wc * 64 + n * 16 + lo;
      float vv[4];
      #pragma unroll
      for (int i = 0; i < 4; ++i) {
        float v = acc[m][n][i];
        if (BIAS) v += bv[n];
        if (ACT == 1) v = fast_tanh(v);
        else if (ACT == 2) v = fmaxf(v, 0.f);
        vv[i] = v;
        if (OMODE == 2) pp[m][i] += v * w3v[n];
      }
      if (OMODE == 1) {
        unsigned int r01 = cvt_pk_bf16(vv[0], vv[1]);
        unsigned int r23 = cvt_pk_bf16(vv[2], vv[3]);
        u16* p = Cb + (size_t)rbase * Nn + c;
        p[0]              = (u16)r01;
        p[Nn]             = (u16)(r01 >> 16);
        p[2 * (size_t)Nn] = (u16)r23;
        p[3 * (size_t)Nn] = (u16)(r23 >> 16);
      } else if (OMODE == 0) {
        float* p = Cf + (size_t)rbase * Nn + c;
        p[0] = vv[0]; p[Nn] = vv[1];
        p[2 * (size_t)Nn] = vv[2]; p[3 * (size_t)Nn] = vv[3];
      }
    }
  }

  if (OMODE == 2) {
    // reduce over the 16 lo-lanes (cols), then across wc via LDS
    #pragma unroll
    for (int m = 0; m < 4; ++m) {
      #pragma unroll
      for (int i = 0; i < 4; ++i) {
        float p = pp[m][i];
        p += __shfl_xor(p, 1, 16);
        p += __shfl_xor(p, 2, 16);
        p += __shfl_xor(p, 4, 16);
        p += __shfl_xor(p, 8, 16);
        if (lo == 0) rs[wc][wr * 64 + m * 16 + hi * 4 + i] = p;
      }
    }
    __syncthreads();
    if (tid < 128) {
      int rr2 = row0 + tid;
      if (rr2 < NR) fout[rr2] = rs[0][tid] + rs[1][tid] + bd3[0];
    }
  }
}

// ----------------------- spmm: pipelined, XCD-sharded -----------------------
template <int F, int CHUNKS, int ACT, bool BIAS, bool OUT_BF16>
__global__ __launch_bounds__(256) void spmm_pl(
    const int* __restrict__ row_ptr, const u32* __restrict__ pack,
    const u16* __restrict__ H, const float* __restrict__ bias,
    void* __restrict__ out, int N) {
  const int ci = blockIdx.x % CHUNKS;
  const int nb = blockIdx.x / CHUNKS;
  const int g = threadIdx.x >> 3;          // 32 nodes/block
  const int gl = threadIdx.x & 7;
  const int node = nb * 32 + g;
  if (node >= N) return;
  const int c0 = ci * (F / CHUNKS) + gl * 8;
  const int beg = row_ptr[node], end = row_ptr[node + 1];

  float a[8] = {};
  int p = beg;
  u32 k0 = 0, k1 = 0, k2 = 0, k3 = 0;
  bool have = (p + 4 <= end);
  if (have) { k0 = pack[p]; k1 = pack[p + 1]; k2 = pack[p + 2]; k3 = pack[p + 3]; }
  while (have) {
    int pn = p + 4;
    bool haven = (pn + 4 <= end);
    u32 n0 = 0, n1 = 0, n2 = 0, n3 = 0;
    if (haven) { n0 = pack[pn]; n1 = pack[pn + 1]; n2 = pack[pn + 2]; n3 = pack[pn + 3]; }
    uint4 h0 = *reinterpret_cast<const uint4*>(&H[(size_t)(k0 & 0xFFFFu) * F + c0]);
    uint4 h1 = *reinterpret_cast<const uint4*>(&H[(size_t)(k1 & 0xFFFFu) * F + c0]);
    uint4 h2 = *reinterpret_cast<const uint4*>(&H[(size_t)(k2 & 0xFFFFu) * F + c0]);
    uint4 h3 = *reinterpret_cast<const uint4*>(&H[(size_t)(k3 & 0xFFFFu) * F + c0]);
    float w0 = hi_f(k0), w1 = hi_f(k1), w2 = hi_f(k2), w3 = hi_f(k3);
    a[0] += w0 * lo_f(h0.x) + w1 * lo_f(h1.x) + w2 * lo_f(h2.x) + w3 * lo_f(h3.x);
    a[1] += w0 * hi_f(h0.x) + w1 * hi_f(h1.x) + w2 * hi_f(h2.x) + w3 * hi_f(h3.x);
    a[2] += w0 * lo_f(h0.y) + w1 * lo_f(h1.y) + w2 * lo_f(h2.y) + w3 * lo_f(h3.y);
    a[3] += w0 * hi_f(h0.y) + w1 * hi_f(h1.y) + w2 * hi_f(h2.y) + w3 * hi_f(h3.y);
    a[4] += w0 * lo_f(h0.z) + w1 * lo_f(h1.z) + w2 * lo_f(h2.z) + w3 * lo_f(h3.z);
    a[5] += w0 * hi_f(h0.z) + w1 * hi_f(h1.z) + w2 * hi_f(h2.z) + w3 * hi_f(h3.z);
    a[6] += w0 * lo_f(h0.w) + w1 * lo_f(h1.w) + w2 * lo_f(h2.w) + w3 * lo_f(h3.w);
    a[7] += w0 * hi_f(h0.w) + w1 * hi_f(h1.w) + w2 * hi_f(h2.w) + w3 * hi_f(h3.w);
    p = pn; k0 = n0; k1 = n1; k2 = n2; k3 = n3; have = haven;
  }
  for (; p < end; ++p) {
    u32 k = pack[p];
    uint4 hv = *reinterpret_cast<const uint4*>(&H[(size_t)(k & 0xFFFFu) * F + c0]);
    float wt = hi_f(k);
    a[0] += wt * lo_f(hv.x); a[1] += wt * hi_f(hv.x);
    a[2] += wt * lo_f(hv.y); a[3] += wt * hi_f(hv.y);
    a[4] += wt * lo_f(hv.z); a[5] += wt * hi_f(hv.z);
    a[6] += wt * lo_f(hv.w); a[7] += wt * hi_f(hv.w);
  }
  if (BIAS) {
    #pragma unroll
    for (int k = 0; k < 8; ++k) a[k] += bias[c0 + k];
  }
  if (ACT == 1) {
    #pragma unroll
    for (int k = 0; k < 8; ++k) a[k] = fast_tanh(a[k]);
  }
  if (OUT_BF16) {
    uint4 o;
    o.x = cvt_pk_bf16(a[0], a[1]);
    o.y = cvt_pk_bf16(a[2], a[3]);
    o.z = cvt_pk_bf16(a[4], a[5]);
    o.w = cvt_pk_bf16(a[6], a[7]);
    *reinterpret_cast<uint4*>(&((u16*)out)[(size_t)node * F + c0]) = o;
  } else {
    float* op = &((float*)out)[(size_t)node * F + c0];
    #pragma unroll
    for (int k = 0; k < 8; ++k) op[k] = a[k];
  }
}

// ---------------------------------------------------------------------------

extern "C" void kernel_launch(void* const* d_in, const int* in_sizes, int n_in,
                              void* d_out, int out_size, void* d_ws, size_t ws_size,
                              hipStream_t stream) {
  const int N = 20000, E = 320000;
  const int F_IN = 512, H1 = 1024, H2 = 512, F_OUT = 128;
  const int D1P = 256, D2P = 128;

  const float* x    = (const float*)d_in[0];
  const int*   src  = (const int*)d_in[1];
  const int*   dst  = (const int*)d_in[2];
  const float* ew   = (const float*)d_in[3];
  const float* W1   = (const float*)d_in[4];
  const float* b1   = (const float*)d_in[5];
  const float* W2   = (const float*)d_in[6];
  const float* b2   = (const float*)d_in[7];
  const float* W3   = (const float*)d_in[8];
  const float* b3   = (const float*)d_in[9];
  const float* Wd1  = (const float*)d_in[10];
  const float* bd1  = (const float*)d_in[11];
  const float* Wd2  = (const float*)d_in[12];
  const float* bd2  = (const float*)d_in[13];
  const float* Wd3  = (const float*)d_in[14];
  const float* bd3  = (const float*)d_in[15];
  float* out = (float*)d_out;

  size_t off = 0;
  auto alloc = [&](size_t bytes) {
    void* p = (char*)d_ws + off;
    off += (bytes + 255) & ~(size_t)255;
    return p;
  };
  u16* xb   = (u16*)alloc((size_t)MPAD * F_IN * 2);    // x bf16; later t2
  u16* ax   = (u16*)alloc((size_t)MPAD * F_IN * 2);    // A@x;   later h2
  u16* h1   = (u16*)alloc((size_t)MPAD * H1 * 2);      // h1 (also t3,gb,d1 region)
  u16* w1t  = (u16*)alloc((size_t)H1 * F_IN * 2);
  u16* w2t  = (u16*)alloc((size_t)H2 * H1 * 2);
  u16* w3t  = (u16*)alloc((size_t)F_OUT * H2 * 2);
  u16* wd1t = (u16*)alloc((size_t)D1P * F_OUT * 2);
  u16* wd2t = (u16*)alloc((size_t)D2P * D1P * 2);
  float* bd1p = (float*)alloc((size_t)D1P * 4);
  float* bd2p = (float*)alloc((size_t)D2P * 4);
  int* row_ptr = (int*)alloc((size_t)(N + 1) * 4);
  int* cnt1    = (int*)alloc((size_t)N * 4);
  int* cnt2    = (int*)alloc((size_t)N * 4);
  int* bsum    = (int*)alloc((size_t)32 * 4);
  u32* csr_pack = (u32*)alloc((size_t)E * 4);

  u16* t2 = xb;
  u16* h2 = ax;
  u16* t3 = h1;
  u16* gb = t3 + (size_t)MPAD * F_OUT;
  u16* d1 = gb + (size_t)MPAD * F_OUT;

  auto cdiv = [](int a, int b) { return (a + b - 1) / b; };
  const int NB32 = cdiv(N, 32);   // 625

  // ---- prep ----
  zero_cnt<<<cdiv(N, 256), 256, 0, stream>>>(cnt1, N);
  prep_all<<<12483, 256, 0, stream>>>(x, xb, W1, w1t, W2, w2t, W3, w3t,
                                      Wd1, wd1t, Wd2, wd2t, bd1, bd1p,
                                      bd2, bd2p, dst, cnt1, cnt2);
  scan_part<<<20, 1024, 0, stream>>>(cnt1, row_ptr, bsum, N);
  scan_fix<<<20, 1024, 0, stream>>>(row_ptr, bsum, N, 20);
  scatter_csr<<<cdiv(E, 256), 256, 0, stream>>>(dst, src, ew, row_ptr, cnt2,
                                                csr_pack, E);

  // ---- layer 1 (reordered): ax = A@x ; h1 = tanh(ax@W1 + b1) ----
  spmm_pl<512, 8, 0, false, true><<<NB32 * 8, 256, 0, stream>>>(
      row_ptr, csr_pack, xb, nullptr, ax, N);
  gemm_mfma_db<1, true, 1><<<dim3(H1 / 128, MPAD / 128), 256, 0, stream>>>(
      ax, w1t, b1, h1, MPAD, F_IN, H1, nullptr, nullptr, nullptr, 0);

  // ---- layer 2: t2 = h1@W2 ; h2 = tanh(A@t2 + b2) ----
  gemm_mfma_db<0, false, 1><<<dim3(H2 / 128, MPAD / 128), 256, 0, stream>>>(
      h1, w2t, nullptr, t2, MPAD, H1, H2, nullptr, nullptr, nullptr, 0);
  spmm_pl<512, 8, 1, true, true><<<NB32 * 8, 256, 0, stream>>>(
      row_ptr, csr_pack, t2, b2, h2, N);

  // ---- layer 3: t3 = h2@W3 ; gb = A@t3 + b3 (bf16) ----
  gemm_mfma_db<0, false, 1><<<dim3(F_OUT / 128, MPAD / 128), 256, 0, stream>>>(
      h2, w3t, nullptr, t3, MPAD, H2, F_OUT, nullptr, nullptr, nullptr, 0);
  spmm_pl<128, 2, 0, true, true><<<NB32 * 2, 256, 0, stream>>>(
      row_ptr, csr_pack, t3, b3, gb, N);

  // ---- dense head: d1 = relu(gb@Wd1+bd1); out = relu(d1@Wd2+bd2)@Wd3+bd3 ----
  gemm_mfma_db<2, true, 1><<<dim3(D1P / 128, MPAD / 128), 256, 0, stream>>>(
      gb, wd1t, bd1p, d1, MPAD, F_OUT, D1P, nullptr, nullptr, nullptr, 0);
  gemm_mfma_db<2, true, 2><<<dim3(D2P / 128, MPAD / 128), 256, 0, stream>>>(
      d1, wd2t, bd2p, nullptr, MPAD, D1P, D2P, Wd3, bd3, out, N);
}